// Round 9
// baseline (662.056 us; speedup 1.0000x reference)
//
#include <hip/hip_runtime.h>
#include <math.h>

// Problem constants (fixed-shape problem)
#define DD 256
#define HH 4
#define CC 64
#define LL 5
#define NEG_SLOPE 0.2f
#define LH 20   // L*H
#define MAXD 768  // LDS softmax-weight cache cap

static __device__ __forceinline__ float lrelu(float x) {
    return x > 0.0f ? x : NEG_SLOPE * x;
}

// ---------------------------------------------------------------------------
// K0: wproj[k][l*4+h] = sum_c gat_ew[l][k][h*64+c] * att_edge[l][h][c]
__global__ __launch_bounds__(256) void wproj_kernel(
    const float* __restrict__ gat_ew, const float* __restrict__ att_edge,
    float* __restrict__ wproj) {
    int l = blockIdx.x;
    int k = threadIdx.x;
    const float* W = gat_ew + (size_t)l * DD * DD;
    const float* att = att_edge + l * DD;  // [H][C] flat = 256
    for (int hh = 0; hh < HH; ++hh) {
        float s = 0.f;
        #pragma unroll
        for (int c = 0; c < CC; ++c)
            s += W[k * DD + hh * CC + c] * att[hh * CC + c];
        wproj[k * LH + l * HH + hh] = s;
    }
}

// K0b: pack per-k weights: wpack[k][0..11]=Wt row, [12..31]=wproj row,
// [32]=eenc_b, pad to 36. Row 256 zero-padded (pipeline prefetch overread).
__global__ __launch_bounds__(256) void wpack_kernel(
    const float* __restrict__ eenc_w, const float* __restrict__ eenc_b,
    const float* __restrict__ wproj, float* __restrict__ wpack) {
    int k = threadIdx.x;
    #pragma unroll
    for (int f = 0; f < 12; ++f) wpack[k * 36 + f] = eenc_w[f * 256 + k];
    #pragma unroll
    for (int j = 0; j < 20; ++j) wpack[k * 36 + 12 + j] = wproj[k * LH + j];
    wpack[k * 36 + 32] = eenc_b[k];
    wpack[k * 36 + 33] = 0.f; wpack[k * 36 + 34] = 0.f; wpack[k * 36 + 35] = 0.f;
    if (k < 36) wpack[256 * 36 + k] = 0.f;  // pad row for prefetch
}

// ---------------------------------------------------------------------------
// K1: node encoder h = relu(x @ enc_w + enc_b)
__global__ __launch_bounds__(256) void encoder_kernel(
    const float* __restrict__ x, const float* __restrict__ enc_w,
    const float* __restrict__ enc_b, float* __restrict__ h, int N) {
    int n = blockIdx.x;
    int tid = threadIdx.x;
    __shared__ float xs[42];
    if (tid < 42) xs[tid] = x[(size_t)n * 42 + tid];
    __syncthreads();
    float acc = enc_b[tid];
    #pragma unroll
    for (int f = 0; f < 42; ++f) acc += xs[f] * enc_w[f * DD + tid];
    h[(size_t)n * DD + tid] = fmaxf(acc, 0.f);
}

// ---------------------------------------------------------------------------
// K2: per-edge a_e[e][l*4+h] = relu(edge_attr[e]@eenc_w + eenc_b) . wproj[:,l*4+h]
// 1 edge/thread. Wave-uniform VMEM weight loads, manually double-buffered
// (prefetch k+1 while computing k) so vmcnt overlaps latency; m0 dot split
// into 3 parallel FMA chains to cut the dependency path.
__global__ __launch_bounds__(256) void edge_pre_kernel(
    const float* __restrict__ edge_attr, const float* __restrict__ wpack,
    float* __restrict__ a_e_all, int E) {
    int tid = threadIdx.x;
    int e = blockIdx.x * 256 + tid;
    bool v = e < E;
    float ea[12] = {};
    if (v) {
        const float4* p = (const float4*)(edge_attr + (size_t)e * 12);
        *(float4*)&ea[0] = p[0]; *(float4*)&ea[4] = p[1]; *(float4*)&ea[8] = p[2];
    }
    float4 acc[5];
    #pragma unroll
    for (int q = 0; q < 5; ++q) acc[q] = make_float4(0.f, 0.f, 0.f, 0.f);
    const float4* wp = (const float4*)wpack;
    // current-k weight set
    float4 wa = wp[0], wb = wp[1], wc = wp[2];
    float4 p0 = wp[3], p1 = wp[4], p2 = wp[5], p3 = wp[6], p4 = wp[7];
    float4 wt = wp[8];
    for (int k = 0; k < 256; ++k) {
        // prefetch k+1 (row 256 is zero pad)
        const float4* np = wp + (k + 1) * 9;
        float4 na = np[0], nb = np[1], nc = np[2];
        float4 q0 = np[3], q1 = np[4], q2 = np[5], q3 = np[6], q4 = np[7];
        float4 nt = np[8];
        // compute k: 3 parallel dot chains
        float s0 = ea[0] * wa.x + ea[1] * wa.y + ea[2] * wa.z + ea[3] * wa.w;
        float s1 = ea[4] * wb.x + ea[5] * wb.y + ea[6] * wb.z + ea[7] * wb.w;
        float s2 = ea[8] * wc.x + ea[9] * wc.y + ea[10] * wc.z + ea[11] * wc.w + wt.x;
        float m0 = fmaxf(s0 + s1 + s2, 0.f);
        acc[0].x += m0 * p0.x; acc[0].y += m0 * p0.y; acc[0].z += m0 * p0.z; acc[0].w += m0 * p0.w;
        acc[1].x += m0 * p1.x; acc[1].y += m0 * p1.y; acc[1].z += m0 * p1.z; acc[1].w += m0 * p1.w;
        acc[2].x += m0 * p2.x; acc[2].y += m0 * p2.y; acc[2].z += m0 * p2.z; acc[2].w += m0 * p2.w;
        acc[3].x += m0 * p3.x; acc[3].y += m0 * p3.y; acc[3].z += m0 * p3.z; acc[3].w += m0 * p3.w;
        acc[4].x += m0 * p4.x; acc[4].y += m0 * p4.y; acc[4].z += m0 * p4.z; acc[4].w += m0 * p4.w;
        // rotate buffers
        wa = na; wb = nb; wc = nc;
        p0 = q0; p1 = q1; p2 = q2; p3 = q3; p4 = q4;
        wt = nt;
    }
    if (v) {
        float4* o = (float4*)(a_e_all + (size_t)e * LH);
        #pragma unroll
        for (int q = 0; q < 5; ++q) o[q] = acc[q];
    }
}

// ---------------------------------------------------------------------------
// deg histogram
__global__ void deg_kernel(const int* __restrict__ dst, int* __restrict__ deg, int E) {
    int e = blockIdx.x * 256 + threadIdx.x;
    if (e < E) atomicAdd(&deg[dst[e]], 1);
}

// K3: self-loop a_e = mean of incoming real-edge a_e (via CSR, no atomics)
__global__ void self_ae_kernel(const int* __restrict__ row_ptr,
                               const int* __restrict__ csr_eid,
                               float* __restrict__ a_e_all, int N, int E) {
    int i = blockIdx.x * 256 + threadIdx.x;
    if (i >= N * LH) return;
    int n = i / LH;
    int j = i % LH;
    int rs = row_ptr[n], re = row_ptr[n + 1];
    float s = 0.f;
    for (int k = rs; k < re; ++k)
        s += a_e_all[(size_t)csr_eid[k] * LH + j];
    a_e_all[(size_t)(E + n) * LH + j] = s / (float)max(re - rs, 1);
}

// ---------------------------------------------------------------------------
// K4: exclusive prefix scan of deg -> row_ptr  (single block)
__global__ __launch_bounds__(1024) void scan_kernel(const int* __restrict__ deg,
                                                    int* __restrict__ row_ptr, int n) {
    __shared__ int buf[1024];
    __shared__ int carry_s;
    int tid = threadIdx.x;
    if (tid == 0) carry_s = 0;
    __syncthreads();
    for (int base = 0; base < n; base += 1024) {
        int i = base + tid;
        int v = (i < n) ? deg[i] : 0;
        buf[tid] = v;
        __syncthreads();
        for (int off = 1; off < 1024; off <<= 1) {
            int t = (tid >= off) ? buf[tid - off] : 0;
            __syncthreads();
            buf[tid] += t;
            __syncthreads();
        }
        int carry = carry_s;
        if (i < n) row_ptr[i] = carry + buf[tid] - v;
        __syncthreads();
        if (tid == 1023) carry_s = carry + buf[1023];
        __syncthreads();
    }
    if (tid == 0) row_ptr[n] = carry_s;
}

__global__ void copy_int_kernel(const int* __restrict__ a, int* __restrict__ b, int n) {
    int i = blockIdx.x * 256 + threadIdx.x;
    if (i < n) b[i] = a[i];
}

// K4c: scatter edges into CSR order by dst
__global__ void scatter_kernel(const int* __restrict__ src, const int* __restrict__ dst,
                               int* __restrict__ cursor, int* __restrict__ csr_src,
                               int* __restrict__ csr_eid, int E) {
    int e = blockIdx.x * 256 + threadIdx.x;
    if (e >= E) return;
    int d = dst[e];
    int pos = atomicAdd(&cursor[d], 1);
    csr_src[pos] = src[e];
    csr_eid[pos] = e;
}

// ---------------------------------------------------------------------------
// GEMM: C[M,256] = A[M,256] @ W[256,256] (+bias, optional relu). fp32, 64x64 tile.
// Fused epilogues:
//  - att_src != nullptr: a_s/a_d per (row, head) from acc (64-col tile == head).
//  - gate_w2 != nullptr: gate partial = sum_j relu(acc+bias)*gate_w2[col],
//    LDS-reduced, atomicAdd per row (gate zeroed by host-side memset).
//    C store skipped when C == nullptr.
__global__ __launch_bounds__(256) void gemm256_kernel(
    const float* __restrict__ A, const float* __restrict__ W,
    const float* __restrict__ bias, float* __restrict__ C, int M, int do_relu,
    const float* __restrict__ att_src, const float* __restrict__ att_dst,
    float* __restrict__ a_s, float* __restrict__ a_d,
    const float* __restrict__ gate_w2, const float* __restrict__ gate_b2,
    float* __restrict__ gate_out) {
    __shared__ __align__(16) float As[16][68];
    __shared__ __align__(16) float Bs[16][68];
    __shared__ float reds[64][17];
    __shared__ float redd[64][17];
    int tid = threadIdx.x;
    int tx = tid & 15, ty = tid >> 4;
    int m0 = blockIdx.x * 64;
    int n0 = blockIdx.y * 64;
    float acc[4][4] = {};
    int arow = tid >> 2, aseg = tid & 3;
    int brow = tid >> 4, bseg = tid & 15;
    for (int k0 = 0; k0 < 256; k0 += 16) {
        float4 av = make_float4(0.f, 0.f, 0.f, 0.f);
        int grow = m0 + arow;
        if (grow < M) av = *(const float4*)(A + (size_t)grow * DD + k0 + aseg * 4);
        As[aseg * 4 + 0][arow] = av.x;
        As[aseg * 4 + 1][arow] = av.y;
        As[aseg * 4 + 2][arow] = av.z;
        As[aseg * 4 + 3][arow] = av.w;
        float4 bv = *(const float4*)(W + (size_t)(k0 + brow) * DD + n0 + bseg * 4);
        *(float4*)&Bs[brow][bseg * 4] = bv;
        __syncthreads();
        #pragma unroll
        for (int kk = 0; kk < 16; ++kk) {
            float4 a4 = *(const float4*)&As[kk][ty * 4];
            float4 b4 = *(const float4*)&Bs[kk][tx * 4];
            acc[0][0] += a4.x * b4.x; acc[0][1] += a4.x * b4.y; acc[0][2] += a4.x * b4.z; acc[0][3] += a4.x * b4.w;
            acc[1][0] += a4.y * b4.x; acc[1][1] += a4.y * b4.y; acc[1][2] += a4.y * b4.z; acc[1][3] += a4.y * b4.w;
            acc[2][0] += a4.z * b4.x; acc[2][1] += a4.z * b4.y; acc[2][2] += a4.z * b4.z; acc[2][3] += a4.z * b4.w;
            acc[3][0] += a4.w * b4.x; acc[3][1] += a4.w * b4.y; acc[3][2] += a4.w * b4.z; acc[3][3] += a4.w * b4.w;
        }
        __syncthreads();
    }
    int colb = n0 + tx * 4;
    if (bias) {
        #pragma unroll
        for (int i = 0; i < 4; ++i) {
            acc[i][0] += bias[colb + 0]; acc[i][1] += bias[colb + 1];
            acc[i][2] += bias[colb + 2]; acc[i][3] += bias[colb + 3];
        }
    }
    if (do_relu) {
        #pragma unroll
        for (int i = 0; i < 4; ++i)
            #pragma unroll
            for (int j = 0; j < 4; ++j) acc[i][j] = fmaxf(acc[i][j], 0.f);
    }
    if (C) {
        #pragma unroll
        for (int i = 0; i < 4; ++i) {
            int r = m0 + ty * 4 + i;
            if (r >= M) continue;
            float4 vv = make_float4(acc[i][0], acc[i][1], acc[i][2], acc[i][3]);
            *(float4*)(C + (size_t)r * DD + colb) = vv;
        }
    }
    if (att_src) {
        float ps[4] = {}, pd[4] = {};
        #pragma unroll
        for (int j = 0; j < 4; ++j) {
            float ws = att_src[colb + j];
            float wd = att_dst[colb + j];
            #pragma unroll
            for (int i = 0; i < 4; ++i) {
                ps[i] += acc[i][j] * ws;
                pd[i] += acc[i][j] * wd;
            }
        }
        #pragma unroll
        for (int i = 0; i < 4; ++i) {
            reds[ty * 4 + i][tx] = ps[i];
            redd[ty * 4 + i][tx] = pd[i];
        }
        __syncthreads();
        if (tid < 64) {
            float ss = 0.f, sd = 0.f;
            #pragma unroll
            for (int t = 0; t < 16; ++t) { ss += reds[tid][t]; sd += redd[tid][t]; }
            int r = m0 + tid;
            if (r < M) {
                a_s[r * HH + blockIdx.y] = ss;
                a_d[r * HH + blockIdx.y] = sd;
            }
        }
    }
    if (gate_w2) {
        float pg[4] = {};
        #pragma unroll
        for (int j = 0; j < 4; ++j) {
            float wg = gate_w2[colb + j];
            #pragma unroll
            for (int i = 0; i < 4; ++i) pg[i] += acc[i][j] * wg;
        }
        #pragma unroll
        for (int i = 0; i < 4; ++i) reds[ty * 4 + i][tx] = pg[i];
        __syncthreads();
        if (tid < 64) {
            float ss = 0.f;
            #pragma unroll
            for (int t = 0; t < 16; ++t) ss += reds[tid][t];
            if (blockIdx.y == 0) ss += gate_b2[0];
            int r = m0 + tid;
            if (r < M) atomicAdd(&gate_out[r], ss);
        }
    }
}

// ---------------------------------------------------------------------------
// K6: fused alpha + softmax attention + aggregation + bias + LN + relu + residual.
__global__ __launch_bounds__(256) void gat_message3_kernel(
    const float* __restrict__ xh, const float* __restrict__ a_s,
    const float* __restrict__ a_d, const float* __restrict__ a_e,  // + l*4; [e][20]
    const int* __restrict__ row_ptr, const int* __restrict__ csr_src,
    const int* __restrict__ csr_eid, const float* __restrict__ gat_b,
    const float* __restrict__ ln_g, const float* __restrict__ ln_b,
    float* __restrict__ h, int N, int E) {
    __shared__ float lw[4][MAXD];   // 12 KB softmax weights
    __shared__ int lsrc[MAXD];      // 3 KB src cache
    __shared__ float s1[256], s2[256];
    int n = blockIdx.x;
    int tid = threadIdx.x;
    int hh = tid >> 6, c = tid & 63;
    int rs = row_ptr[n], re = row_ptr[n + 1];
    int deg = re - rs;
    float adn = a_d[n * HH + hh];
    float al_self = lrelu(a_s[n * HH + hh] + adn + a_e[(size_t)(E + n) * LH + hh]);
    // pass 1: merged online max+denom; compute alpha inline, cache in LDS
    float m = al_self, den = 0.f;
    for (int k = rs + c; k < re; k += 64) {
        int kk = k - rs;
        int s = csr_src[k];
        int eid = csr_eid[k];
        float a = lrelu(a_s[s * HH + hh] + adn + a_e[(size_t)eid * LH + hh]);
        if (kk < MAXD) {
            lw[hh][kk] = a;
            if (hh == 0) lsrc[kk] = s;
        }
        float mn = fmaxf(m, a);
        den = den * __expf(m - mn) + __expf(a - mn);
        m = mn;
    }
    #pragma unroll
    for (int off = 32; off; off >>= 1) {
        float m2 = __shfl_xor(m, off, 64);
        float d2 = __shfl_xor(den, off, 64);
        float mn = fmaxf(m, m2);
        den = den * __expf(m - mn) + d2 * __expf(m2 - mn);
        m = mn;
    }
    den += __expf(al_self - m);
    float inv_den = 1.0f / den;
    // convert cached alpha -> softmax weight (wave-private rows)
    int cap = min(deg, MAXD);
    for (int kk = c; kk < cap; kk += 64)
        lw[hh][kk] = __expf(lw[hh][kk] - m) * inv_den;
    __syncthreads();  // publish lsrc (wave 0) to all waves
    // pass 3: aggregation; weights + src via LDS broadcast, xh rows coalesced
    float acc = __expf(al_self - m) * inv_den * xh[(size_t)n * DD + tid];
    for (int k = rs; k < re; ++k) {
        int kk = k - rs;
        int s;
        float w;
        if (kk < MAXD) { s = lsrc[kk]; w = lw[hh][kk]; }
        else {
            s = csr_src[k];
            float a = lrelu(a_s[s * HH + hh] + adn + a_e[(size_t)csr_eid[k] * LH + hh]);
            w = __expf(a - m) * inv_den;
        }
        acc += w * xh[(size_t)s * DD + tid];
    }
    float val = acc + gat_b[tid];
    s1[tid] = val;
    s2[tid] = val * val;
    __syncthreads();
    for (int off = 128; off; off >>= 1) {
        if (tid < off) { s1[tid] += s1[tid + off]; s2[tid] += s2[tid + off]; }
        __syncthreads();
    }
    float mu = s1[0] * (1.0f / DD);
    float var = s2[0] * (1.0f / DD) - mu * mu;
    float normed = (val - mu) * rsqrtf(var + 1e-5f) * ln_g[tid] + ln_b[tid];
    h[(size_t)n * DD + tid] += fmaxf(normed, 0.f);
}

// ---------------------------------------------------------------------------
// K7pre: batch segment boundaries (batch is sorted)
__global__ void bstart_kernel(const int* __restrict__ batch, int* __restrict__ bstart,
                              int N, int B) {
    int b = threadIdx.x;
    if (b > B) return;
    int lo = 0, hi = N;
    while (lo < hi) {
        int mid = (lo + hi) >> 1;
        if (batch[mid] < b) lo = mid + 1; else hi = mid;
    }
    bstart[b] = lo;
}

// K7a: per-graph gate max + denom (B blocks)
__global__ __launch_bounds__(256) void gseg_kernel(
    const float* __restrict__ gate, const int* __restrict__ bstart,
    float* __restrict__ gmax, float* __restrict__ gden) {
    int b = blockIdx.x;
    int tid = threadIdx.x;
    int s0 = bstart[b], s1 = bstart[b + 1];
    __shared__ float red[256];
    float m = -1e30f;
    for (int i = s0 + tid; i < s1; i += 256) m = fmaxf(m, gate[i]);
    red[tid] = m;
    __syncthreads();
    for (int off = 128; off; off >>= 1) {
        if (tid < off) red[tid] = fmaxf(red[tid], red[tid + off]);
        __syncthreads();
    }
    float gm = red[0];
    __syncthreads();
    float s = 0.f;
    for (int i = s0 + tid; i < s1; i += 256) s += __expf(gate[i] - gm);
    red[tid] = s;
    __syncthreads();
    for (int off = 128; off; off >>= 1) {
        if (tid < off) red[tid] += red[tid + off];
        __syncthreads();
    }
    if (tid == 0) {
        gmax[b] = gm;
        gden[b] = red[0];
    }
}

// K7c: per-node pooling weight
__global__ void wgt_kernel(const float* __restrict__ gate, const int* __restrict__ batch,
                           const float* __restrict__ gmax, const float* __restrict__ gden,
                           float* __restrict__ wgt, int N) {
    int n = blockIdx.x * 256 + threadIdx.x;
    if (n >= N) return;
    int b = batch[n];
    wgt[n] = __expf(gate[n] - gmax[b]) / gden[b];
}

// K7d: scatter-accumulate pooled embedding.
#define POOL_CHUNK 32
__global__ __launch_bounds__(256) void pool_scatter_kernel(
    const float* __restrict__ h, const float* __restrict__ wgt,
    const int* __restrict__ batch, float* __restrict__ g_embed, int N) {
    int i0 = blockIdx.x * POOL_CHUNK;
    int d = threadIdx.x;
    int iend = min(i0 + POOL_CHUNK, N);
    float acc = 0.f;
    int cur = batch[i0];
    for (int i = i0; i < iend; ++i) {
        int b = batch[i];
        if (b != cur) {
            atomicAdd(&g_embed[cur * DD + d], acc);
            acc = 0.f;
            cur = b;
        }
        acc += wgt[i] * h[(size_t)i * DD + d];
    }
    atomicAdd(&g_embed[cur * DD + d], acc);
}

// K8: readout MLP [B,256] -> [B,256]
__global__ __launch_bounds__(256) void readout_kernel(
    const float* __restrict__ g_embed, const float* __restrict__ w1,
    const float* __restrict__ b1, const float* __restrict__ w2,
    const float* __restrict__ b2, float* __restrict__ out) {
    int b = blockIdx.x;
    int tid = threadIdx.x;
    __shared__ float gvec[256];
    __shared__ float hid[256];
    gvec[tid] = g_embed[b * DD + tid];
    __syncthreads();
    float hv = b1[tid];
    for (int k = 0; k < DD; ++k) hv += gvec[k] * w1[k * DD + tid];
    hid[tid] = fmaxf(hv, 0.f);
    __syncthreads();
    float o = b2[tid];
    for (int t = 0; t < DD; ++t) o += hid[t] * w2[t * DD + tid];
    out[b * DD + tid] = o;
}

// ---------------------------------------------------------------------------
extern "C" void kernel_launch(void* const* d_in, const int* in_sizes, int n_in,
                              void* d_out, int out_size, void* d_ws, size_t ws_size,
                              hipStream_t stream) {
    const float* x        = (const float*)d_in[0];
    const float* edge_attr= (const float*)d_in[1];
    const int*   edge_idx = (const int*)d_in[2];
    const int*   batch    = (const int*)d_in[3];
    const float* enc_w    = (const float*)d_in[4];
    const float* enc_b    = (const float*)d_in[5];
    const float* eenc_w   = (const float*)d_in[6];
    const float* eenc_b   = (const float*)d_in[7];
    const float* gat_w    = (const float*)d_in[8];
    const float* att_src  = (const float*)d_in[9];
    const float* att_dst  = (const float*)d_in[10];
    const float* att_edge = (const float*)d_in[11];
    const float* gat_ew   = (const float*)d_in[12];
    const float* gat_b    = (const float*)d_in[13];
    const float* ln_g     = (const float*)d_in[14];
    const float* ln_b     = (const float*)d_in[15];
    const float* gate_w1  = (const float*)d_in[16];
    const float* gate_b1  = (const float*)d_in[17];
    const float* gate_w2  = (const float*)d_in[18];
    const float* gate_b2  = (const float*)d_in[19];
    const float* ro_w1    = (const float*)d_in[20];
    const float* ro_b1    = (const float*)d_in[21];
    const float* ro_w2    = (const float*)d_in[22];
    const float* ro_b2    = (const float*)d_in[23];
    float* out = (float*)d_out;

    const int N = in_sizes[0] / 42;       // 10000
    const int E = in_sizes[1] / 12;       // 160000
    const int B = out_size / DD;          // 16

    // workspace carve-up
    char* p = (char*)d_ws;
    auto alloc = [&](size_t bytes) {
        char* r = p;
        p += (bytes + 255) & ~(size_t)255;
        return (void*)r;
    };
    float* h        = (float*)alloc((size_t)N * DD * 4);
    float* xh       = (float*)alloc((size_t)N * DD * 4);
    float* a_s      = (float*)alloc((size_t)N * HH * 4);
    float* a_d      = (float*)alloc((size_t)N * HH * 4);
    float* a_e_all  = (float*)alloc((size_t)(E + N) * LH * 4);  // [e][l*4+h]
    float* wproj    = (float*)alloc((size_t)DD * LH * 4);
    float* wpack    = (float*)alloc((size_t)(DD + 1) * 36 * 4);
    float* gate     = (float*)alloc((size_t)N * 4);
    float* g_embed  = (float*)alloc((size_t)B * DD * 4);
    float* gmax     = (float*)alloc((size_t)B * 4);
    float* gden     = (float*)alloc((size_t)B * 4);
    float* wgt      = (float*)alloc((size_t)N * 4);
    int* deg        = (int*)alloc((size_t)N * 4);
    int* row_ptr    = (int*)alloc((size_t)(N + 1) * 4);
    int* cursor     = (int*)alloc((size_t)N * 4);
    int* csr_src    = (int*)alloc((size_t)E * 4);
    int* csr_eid    = (int*)alloc((size_t)E * 4);
    int* bstart     = (int*)alloc((size_t)(B + 1) * 4);

    const int* src_arr = edge_idx;
    const int* dst_arr = edge_idx + E;

    hipMemsetAsync(deg, 0, (size_t)N * 4, stream);
    hipMemsetAsync(g_embed, 0, (size_t)B * DD * 4, stream);
    hipMemsetAsync(gate, 0, (size_t)N * 4, stream);

    wproj_kernel<<<LL, 256, 0, stream>>>(gat_ew, att_edge, wproj);
    wpack_kernel<<<1, 256, 0, stream>>>(eenc_w, eenc_b, wproj, wpack);
    encoder_kernel<<<N, 256, 0, stream>>>(x, enc_w, enc_b, h, N);
    deg_kernel<<<(E + 255) / 256, 256, 0, stream>>>(dst_arr, deg, E);
    scan_kernel<<<1, 1024, 0, stream>>>(deg, row_ptr, N);
    copy_int_kernel<<<(N + 255) / 256, 256, 0, stream>>>(row_ptr, cursor, N);
    scatter_kernel<<<(E + 255) / 256, 256, 0, stream>>>(
        src_arr, dst_arr, cursor, csr_src, csr_eid, E);
    edge_pre_kernel<<<(E + 255) / 256, 256, 0, stream>>>(
        edge_attr, wpack, a_e_all, E);
    self_ae_kernel<<<(N * LH + 255) / 256, 256, 0, stream>>>(
        row_ptr, csr_eid, a_e_all, N, E);

    dim3 ggrid((N + 63) / 64, 4);
    for (int l = 0; l < LL; ++l) {
        gemm256_kernel<<<ggrid, 256, 0, stream>>>(
            h, gat_w + (size_t)l * DD * DD, nullptr, xh, N, 0,
            att_src + l * DD, att_dst + l * DD, a_s, a_d,
            nullptr, nullptr, nullptr);
        gat_message3_kernel<<<N, 256, 0, stream>>>(
            xh, a_s, a_d, a_e_all + l * HH, row_ptr, csr_src, csr_eid,
            gat_b + l * DD, ln_g + l * DD, ln_b + l * DD, h, N, E);
    }

    // pooling gate: gate[n] = relu(h@gate_w1+b1) . gate_w2 + b2, fused into GEMM
    gemm256_kernel<<<ggrid, 256, 0, stream>>>(h, gate_w1, gate_b1, nullptr, N, 1,
                                              nullptr, nullptr, nullptr, nullptr,
                                              gate_w2, gate_b2, gate);
    bstart_kernel<<<1, 32, 0, stream>>>(batch, bstart, N, B);
    gseg_kernel<<<B, 256, 0, stream>>>(gate, bstart, gmax, gden);
    wgt_kernel<<<(N + 255) / 256, 256, 0, stream>>>(gate, batch, gmax, gden, wgt, N);
    pool_scatter_kernel<<<(N + POOL_CHUNK - 1) / POOL_CHUNK, 256, 0, stream>>>(
        h, wgt, batch, g_embed, N);
    readout_kernel<<<B, 256, 0, stream>>>(g_embed, ro_w1, ro_b1, ro_w2, ro_b2, out);
}

// Round 10
// 571.971 us; speedup vs baseline: 1.1575x; 1.1575x over previous
//
#include <hip/hip_runtime.h>
#include <math.h>

// Problem constants (fixed-shape problem)
#define DD 256
#define HH 4
#define CC 64
#define LL 5
#define NEG_SLOPE 0.2f
#define LH 20   // L*H
#define MAXD 768  // LDS softmax-weight cache cap

typedef __bf16 bf16x8 __attribute__((ext_vector_type(8)));
typedef float f32x4 __attribute__((ext_vector_type(4)));

static __device__ __forceinline__ float lrelu(float x) {
    return x > 0.0f ? x : NEG_SLOPE * x;
}

// ---------------------------------------------------------------------------
// K0: wproj[k][l*4+h] = sum_c gat_ew[l][k][h*64+c] * att_edge[l][h][c]
__global__ __launch_bounds__(256) void wproj_kernel(
    const float* __restrict__ gat_ew, const float* __restrict__ att_edge,
    float* __restrict__ wproj) {
    int l = blockIdx.x;
    int k = threadIdx.x;
    const float* W = gat_ew + (size_t)l * DD * DD;
    const float* att = att_edge + l * DD;  // [H][C] flat = 256
    for (int hh = 0; hh < HH; ++hh) {
        float s = 0.f;
        #pragma unroll
        for (int c = 0; c < CC; ++c)
            s += W[k * DD + hh * CC + c] * att[hh * CC + c];
        wproj[k * LH + l * HH + hh] = s;
    }
}

// K0b: pack per-k weights: wpack[k][0..11]=Wt row, [12..31]=wproj row, [32]=eenc_b
__global__ __launch_bounds__(256) void wpack_kernel(
    const float* __restrict__ eenc_w, const float* __restrict__ eenc_b,
    const float* __restrict__ wproj, float* __restrict__ wpack) {
    int k = threadIdx.x;
    #pragma unroll
    for (int f = 0; f < 12; ++f) wpack[k * 36 + f] = eenc_w[f * 256 + k];
    #pragma unroll
    for (int j = 0; j < 20; ++j) wpack[k * 36 + 12 + j] = wproj[k * LH + j];
    wpack[k * 36 + 32] = eenc_b[k];
    wpack[k * 36 + 33] = 0.f; wpack[k * 36 + 34] = 0.f; wpack[k * 36 + 35] = 0.f;
}

// K0c: swizzle GEMM weights into MFMA B-fragment order, bf16.
// wf element (((l*32 + y*8 + ks)*4 + t)*64 + lane)*8 + j =
//   W_l[ks*32 + (lane>>4)*8 + j][y*64 + t*16 + (lane&15)]
// l in 0..4 = gat_w layers; l = 5 = gate_w1.
__global__ __launch_bounds__(256) void wswizzle_kernel(
    const float* __restrict__ gat_w, const float* __restrict__ gate_w1,
    __bf16* __restrict__ wf) {
    int b = blockIdx.x;           // l*32 + y*8 + ks
    int l = b >> 5;
    int rem = b & 31;
    int y = rem >> 3, ks = rem & 7;
    int tid = threadIdx.x;
    int t = tid >> 6, lane = tid & 63;
    int q = lane >> 4, r15 = lane & 15;
    const float* W = (l < 5) ? (gat_w + (size_t)l * DD * DD) : gate_w1;
    size_t obase = (((size_t)b * 4 + t) * 64 + lane) * 8;
    int kbase = ks * 32 + q * 8;
    int col = y * 64 + t * 16 + r15;
    #pragma unroll
    for (int j = 0; j < 8; ++j)
        wf[obase + j] = (__bf16)W[(size_t)(kbase + j) * DD + col];
}

// ---------------------------------------------------------------------------
// K1: node encoder h = relu(x @ enc_w + enc_b); also writes bf16 shadow
__global__ __launch_bounds__(256) void encoder_kernel(
    const float* __restrict__ x, const float* __restrict__ enc_w,
    const float* __restrict__ enc_b, float* __restrict__ h,
    __bf16* __restrict__ hbf, int N) {
    int n = blockIdx.x;
    int tid = threadIdx.x;
    __shared__ float xs[42];
    if (tid < 42) xs[tid] = x[(size_t)n * 42 + tid];
    __syncthreads();
    float acc = enc_b[tid];
    #pragma unroll
    for (int f = 0; f < 42; ++f) acc += xs[f] * enc_w[f * DD + tid];
    float v = fmaxf(acc, 0.f);
    h[(size_t)n * DD + tid] = v;
    hbf[(size_t)n * DD + tid] = (__bf16)v;
}

// ---------------------------------------------------------------------------
// K2: per-edge a_e (R7 form — compiler-scheduled, no manual pipeline).
__global__ __launch_bounds__(256) void edge_pre_kernel(
    const float* __restrict__ edge_attr, const float* __restrict__ wpack,
    float* __restrict__ a_e_all, int E) {
    int tid = threadIdx.x;
    int e = blockIdx.x * 256 + tid;
    bool v = e < E;
    float ea[12] = {};
    if (v) {
        const float4* p = (const float4*)(edge_attr + (size_t)e * 12);
        *(float4*)&ea[0] = p[0]; *(float4*)&ea[4] = p[1]; *(float4*)&ea[8] = p[2];
    }
    float4 acc[5];
    #pragma unroll
    for (int q = 0; q < 5; ++q) acc[q] = make_float4(0.f, 0.f, 0.f, 0.f);
    for (int k = 0; k < 256; ++k) {
        const float4* wp = (const float4*)(wpack + k * 36);
        float4 wa = wp[0], wb = wp[1], wc = wp[2];
        float4 wt = wp[8];  // .x = bias
        float m0 = wt.x;
        m0 += ea[0] * wa.x + ea[1] * wa.y + ea[2] * wa.z + ea[3] * wa.w
            + ea[4] * wb.x + ea[5] * wb.y + ea[6] * wb.z + ea[7] * wb.w
            + ea[8] * wc.x + ea[9] * wc.y + ea[10] * wc.z + ea[11] * wc.w;
        m0 = fmaxf(m0, 0.f);
        float4 p0 = wp[3], p1 = wp[4], p2 = wp[5], p3 = wp[6], p4 = wp[7];
        acc[0].x += m0 * p0.x; acc[0].y += m0 * p0.y; acc[0].z += m0 * p0.z; acc[0].w += m0 * p0.w;
        acc[1].x += m0 * p1.x; acc[1].y += m0 * p1.y; acc[1].z += m0 * p1.z; acc[1].w += m0 * p1.w;
        acc[2].x += m0 * p2.x; acc[2].y += m0 * p2.y; acc[2].z += m0 * p2.z; acc[2].w += m0 * p2.w;
        acc[3].x += m0 * p3.x; acc[3].y += m0 * p3.y; acc[3].z += m0 * p3.z; acc[3].w += m0 * p3.w;
        acc[4].x += m0 * p4.x; acc[4].y += m0 * p4.y; acc[4].z += m0 * p4.z; acc[4].w += m0 * p4.w;
    }
    if (v) {
        float4* o = (float4*)(a_e_all + (size_t)e * LH);
        #pragma unroll
        for (int q = 0; q < 5; ++q) o[q] = acc[q];
    }
}

// ---------------------------------------------------------------------------
__global__ void deg_kernel(const int* __restrict__ dst, int* __restrict__ deg, int E) {
    int e = blockIdx.x * 256 + threadIdx.x;
    if (e < E) atomicAdd(&deg[dst[e]], 1);
}

__global__ void self_ae_kernel(const int* __restrict__ row_ptr,
                               const int* __restrict__ csr_eid,
                               float* __restrict__ a_e_all, int N, int E) {
    int i = blockIdx.x * 256 + threadIdx.x;
    if (i >= N * LH) return;
    int n = i / LH;
    int j = i % LH;
    int rs = row_ptr[n], re = row_ptr[n + 1];
    float s = 0.f;
    for (int k = rs; k < re; ++k)
        s += a_e_all[(size_t)csr_eid[k] * LH + j];
    a_e_all[(size_t)(E + n) * LH + j] = s / (float)max(re - rs, 1);
}

__global__ __launch_bounds__(1024) void scan_kernel(const int* __restrict__ deg,
                                                    int* __restrict__ row_ptr, int n) {
    __shared__ int buf[1024];
    __shared__ int carry_s;
    int tid = threadIdx.x;
    if (tid == 0) carry_s = 0;
    __syncthreads();
    for (int base = 0; base < n; base += 1024) {
        int i = base + tid;
        int v = (i < n) ? deg[i] : 0;
        buf[tid] = v;
        __syncthreads();
        for (int off = 1; off < 1024; off <<= 1) {
            int t = (tid >= off) ? buf[tid - off] : 0;
            __syncthreads();
            buf[tid] += t;
            __syncthreads();
        }
        int carry = carry_s;
        if (i < n) row_ptr[i] = carry + buf[tid] - v;
        __syncthreads();
        if (tid == 1023) carry_s = carry + buf[1023];
        __syncthreads();
    }
    if (tid == 0) row_ptr[n] = carry_s;
}

__global__ void copy_int_kernel(const int* __restrict__ a, int* __restrict__ b, int n) {
    int i = blockIdx.x * 256 + threadIdx.x;
    if (i < n) b[i] = a[i];
}

__global__ void scatter_kernel(const int* __restrict__ src, const int* __restrict__ dst,
                               int* __restrict__ cursor, int* __restrict__ csr_src,
                               int* __restrict__ csr_eid, int E) {
    int e = blockIdx.x * 256 + threadIdx.x;
    if (e >= E) return;
    int d = dst[e];
    int pos = atomicAdd(&cursor[d], 1);
    csr_src[pos] = src[e];
    csr_eid[pos] = e;
}

// ---------------------------------------------------------------------------
// MFMA GEMM: xh[M,256] = hbf @ W (bf16 in, fp32 acc). Block 256 thr = 4 waves;
// tile 64 rows x 64 cols (blockIdx.y = column quarter == head). Wave w: rows
// m0+16w..+15 as four 16x16x32 chains over K=256. B frags from pre-swizzled wf
// (1 dwordx4/lane/step, coalesced); A frags direct from hbf. No LDS/barriers.
// Epilogues: att path (a_s/a_d per head, 16-lane shuffle reduce) or gate path
// (bias+relu+dot gate_w2, atomicAdd).
__global__ __launch_bounds__(256) void gemm_mfma_kernel(
    const __bf16* __restrict__ hbf, const __bf16* __restrict__ wf,  // this layer's 65536-elem slice
    float* __restrict__ xh, int M,
    const float* __restrict__ att_src, const float* __restrict__ att_dst,
    float* __restrict__ a_s, float* __restrict__ a_d,
    const float* __restrict__ bias, const float* __restrict__ gate_w2,
    const float* __restrict__ gate_b2, float* __restrict__ gate_out) {
    int tid = threadIdx.x;
    int w = tid >> 6, lane = tid & 63;
    int q = lane >> 4, r15 = lane & 15;
    int m0 = blockIdx.x * 64;
    int y = blockIdx.y;
    int arow = m0 + w * 16 + r15;
    int arowc = min(arow, M - 1);
    const __bf16* ap = hbf + (size_t)arowc * DD + q * 8;
    const bf16x8* bp0 = (const bf16x8*)wf + (size_t)(y * 8) * 4 * 64 + lane;
    f32x4 acc[4];
    #pragma unroll
    for (int t = 0; t < 4; ++t) acc[t] = (f32x4){0.f, 0.f, 0.f, 0.f};
    #pragma unroll
    for (int ks = 0; ks < 8; ++ks) {
        bf16x8 a = *(const bf16x8*)(ap + ks * 32);
        const bf16x8* bp = bp0 + (size_t)ks * 4 * 64;
        #pragma unroll
        for (int t = 0; t < 4; ++t) {
            bf16x8 b = bp[(size_t)t * 64];
            acc[t] = __builtin_amdgcn_mfma_f32_16x16x32_bf16(a, b, acc[t], 0, 0, 0);
        }
    }
    // C/D: lane holds rows q*4+r (r=0..3), col r15, per n-subtile t.
    if (xh) {
        #pragma unroll
        for (int t = 0; t < 4; ++t) {
            int col = y * 64 + t * 16 + r15;
            #pragma unroll
            for (int r = 0; r < 4; ++r) {
                int rc = m0 + w * 16 + q * 4 + r;
                if (rc < M) xh[(size_t)rc * DD + col] = acc[t][r];
            }
        }
    }
    if (att_src) {
        #pragma unroll
        for (int r = 0; r < 4; ++r) {
            float ps = 0.f, pd = 0.f;
            #pragma unroll
            for (int t = 0; t < 4; ++t) {
                int col = y * 64 + t * 16 + r15;
                ps += acc[t][r] * att_src[col];
                pd += acc[t][r] * att_dst[col];
            }
            #pragma unroll
            for (int mask = 1; mask < 16; mask <<= 1) {
                ps += __shfl_xor(ps, mask, 64);
                pd += __shfl_xor(pd, mask, 64);
            }
            int rc = m0 + w * 16 + q * 4 + r;
            if (r15 == 0 && rc < M) {
                a_s[rc * HH + y] = ps;
                a_d[rc * HH + y] = pd;
            }
        }
    }
    if (gate_w2) {
        #pragma unroll
        for (int r = 0; r < 4; ++r) {
            float pg = 0.f;
            #pragma unroll
            for (int t = 0; t < 4; ++t) {
                int col = y * 64 + t * 16 + r15;
                pg += fmaxf(acc[t][r] + bias[col], 0.f) * gate_w2[col];
            }
            #pragma unroll
            for (int mask = 1; mask < 16; mask <<= 1) pg += __shfl_xor(pg, mask, 64);
            int rc = m0 + w * 16 + q * 4 + r;
            if (r15 == 0 && rc < M) {
                float add = pg + (y == 0 ? gate_b2[0] : 0.f);
                atomicAdd(&gate_out[rc], add);
            }
        }
    }
}

// ---------------------------------------------------------------------------
// K6: fused alpha + softmax attention + aggregation + bias + LN + relu + residual.
// Also maintains the bf16 shadow of h for the next layer's MFMA GEMM.
__global__ __launch_bounds__(256) void gat_message3_kernel(
    const float* __restrict__ xh, const float* __restrict__ a_s,
    const float* __restrict__ a_d, const float* __restrict__ a_e,  // + l*4; [e][20]
    const int* __restrict__ row_ptr, const int* __restrict__ csr_src,
    const int* __restrict__ csr_eid, const float* __restrict__ gat_b,
    const float* __restrict__ ln_g, const float* __restrict__ ln_b,
    float* __restrict__ h, __bf16* __restrict__ hbf, int N, int E) {
    __shared__ float lw[4][MAXD];   // 12 KB softmax weights
    __shared__ int lsrc[MAXD];      // 3 KB src cache
    __shared__ float s1[256], s2[256];
    int n = blockIdx.x;
    int tid = threadIdx.x;
    int hh = tid >> 6, c = tid & 63;
    int rs = row_ptr[n], re = row_ptr[n + 1];
    int deg = re - rs;
    float adn = a_d[n * HH + hh];
    float al_self = lrelu(a_s[n * HH + hh] + adn + a_e[(size_t)(E + n) * LH + hh]);
    float m = al_self, den = 0.f;
    for (int k = rs + c; k < re; k += 64) {
        int kk = k - rs;
        int s = csr_src[k];
        int eid = csr_eid[k];
        float a = lrelu(a_s[s * HH + hh] + adn + a_e[(size_t)eid * LH + hh]);
        if (kk < MAXD) {
            lw[hh][kk] = a;
            if (hh == 0) lsrc[kk] = s;
        }
        float mn = fmaxf(m, a);
        den = den * __expf(m - mn) + __expf(a - mn);
        m = mn;
    }
    #pragma unroll
    for (int off = 32; off; off >>= 1) {
        float m2 = __shfl_xor(m, off, 64);
        float d2 = __shfl_xor(den, off, 64);
        float mn = fmaxf(m, m2);
        den = den * __expf(m - mn) + d2 * __expf(m2 - mn);
        m = mn;
    }
    den += __expf(al_self - m);
    float inv_den = 1.0f / den;
    int cap = min(deg, MAXD);
    for (int kk = c; kk < cap; kk += 64)
        lw[hh][kk] = __expf(lw[hh][kk] - m) * inv_den;
    __syncthreads();  // publish lsrc (wave 0) to all waves
    float acc = __expf(al_self - m) * inv_den * xh[(size_t)n * DD + tid];
    for (int k = rs; k < re; ++k) {
        int kk = k - rs;
        int s;
        float wgt;
        if (kk < MAXD) { s = lsrc[kk]; wgt = lw[hh][kk]; }
        else {
            s = csr_src[k];
            float a = lrelu(a_s[s * HH + hh] + adn + a_e[(size_t)csr_eid[k] * LH + hh]);
            wgt = __expf(a - m) * inv_den;
        }
        acc += wgt * xh[(size_t)s * DD + tid];
    }
    float val = acc + gat_b[tid];
    s1[tid] = val;
    s2[tid] = val * val;
    __syncthreads();
    for (int off = 128; off; off >>= 1) {
        if (tid < off) { s1[tid] += s1[tid + off]; s2[tid] += s2[tid + off]; }
        __syncthreads();
    }
    float mu = s1[0] * (1.0f / DD);
    float var = s2[0] * (1.0f / DD) - mu * mu;
    float normed = (val - mu) * rsqrtf(var + 1e-5f) * ln_g[tid] + ln_b[tid];
    size_t idx = (size_t)n * DD + tid;
    float hn = h[idx] + fmaxf(normed, 0.f);
    h[idx] = hn;
    hbf[idx] = (__bf16)hn;
}

// ---------------------------------------------------------------------------
__global__ void bstart_kernel(const int* __restrict__ batch, int* __restrict__ bstart,
                              int N, int B) {
    int b = threadIdx.x;
    if (b > B) return;
    int lo = 0, hi = N;
    while (lo < hi) {
        int mid = (lo + hi) >> 1;
        if (batch[mid] < b) lo = mid + 1; else hi = mid;
    }
    bstart[b] = lo;
}

__global__ __launch_bounds__(256) void gseg_kernel(
    const float* __restrict__ gate, const int* __restrict__ bstart,
    float* __restrict__ gmax, float* __restrict__ gden) {
    int b = blockIdx.x;
    int tid = threadIdx.x;
    int s0 = bstart[b], s1 = bstart[b + 1];
    __shared__ float red[256];
    float m = -1e30f;
    for (int i = s0 + tid; i < s1; i += 256) m = fmaxf(m, gate[i]);
    red[tid] = m;
    __syncthreads();
    for (int off = 128; off; off >>= 1) {
        if (tid < off) red[tid] = fmaxf(red[tid], red[tid + off]);
        __syncthreads();
    }
    float gm = red[0];
    __syncthreads();
    float s = 0.f;
    for (int i = s0 + tid; i < s1; i += 256) s += __expf(gate[i] - gm);
    red[tid] = s;
    __syncthreads();
    for (int off = 128; off; off >>= 1) {
        if (tid < off) red[tid] += red[tid + off];
        __syncthreads();
    }
    if (tid == 0) {
        gmax[b] = gm;
        gden[b] = red[0];
    }
}

__global__ void wgt_kernel(const float* __restrict__ gate, const int* __restrict__ batch,
                           const float* __restrict__ gmax, const float* __restrict__ gden,
                           float* __restrict__ wgt, int N) {
    int n = blockIdx.x * 256 + threadIdx.x;
    if (n >= N) return;
    int b = batch[n];
    wgt[n] = __expf(gate[n] - gmax[b]) / gden[b];
}

#define POOL_CHUNK 32
__global__ __launch_bounds__(256) void pool_scatter_kernel(
    const float* __restrict__ h, const float* __restrict__ wgt,
    const int* __restrict__ batch, float* __restrict__ g_embed, int N) {
    int i0 = blockIdx.x * POOL_CHUNK;
    int d = threadIdx.x;
    int iend = min(i0 + POOL_CHUNK, N);
    float acc = 0.f;
    int cur = batch[i0];
    for (int i = i0; i < iend; ++i) {
        int b = batch[i];
        if (b != cur) {
            atomicAdd(&g_embed[cur * DD + d], acc);
            acc = 0.f;
            cur = b;
        }
        acc += wgt[i] * h[(size_t)i * DD + d];
    }
    atomicAdd(&g_embed[cur * DD + d], acc);
}

__global__ __launch_bounds__(256) void readout_kernel(
    const float* __restrict__ g_embed, const float* __restrict__ w1,
    const float* __restrict__ b1, const float* __restrict__ w2,
    const float* __restrict__ b2, float* __restrict__ out) {
    int b = blockIdx.x;
    int tid = threadIdx.x;
    __shared__ float gvec[256];
    __shared__ float hid[256];
    gvec[tid] = g_embed[b * DD + tid];
    __syncthreads();
    float hv = b1[tid];
    for (int k = 0; k < DD; ++k) hv += gvec[k] * w1[k * DD + tid];
    hid[tid] = fmaxf(hv, 0.f);
    __syncthreads();
    float o = b2[tid];
    for (int t = 0; t < DD; ++t) o += hid[t] * w2[t * DD + tid];
    out[b * DD + tid] = o;
}

// ---------------------------------------------------------------------------
extern "C" void kernel_launch(void* const* d_in, const int* in_sizes, int n_in,
                              void* d_out, int out_size, void* d_ws, size_t ws_size,
                              hipStream_t stream) {
    const float* x        = (const float*)d_in[0];
    const float* edge_attr= (const float*)d_in[1];
    const int*   edge_idx = (const int*)d_in[2];
    const int*   batch    = (const int*)d_in[3];
    const float* enc_w    = (const float*)d_in[4];
    const float* enc_b    = (const float*)d_in[5];
    const float* eenc_w   = (const float*)d_in[6];
    const float* eenc_b   = (const float*)d_in[7];
    const float* gat_w    = (const float*)d_in[8];
    const float* att_src  = (const float*)d_in[9];
    const float* att_dst  = (const float*)d_in[10];
    const float* att_edge = (const float*)d_in[11];
    const float* gat_ew   = (const float*)d_in[12];
    const float* gat_b    = (const float*)d_in[13];
    const float* ln_g     = (const float*)d_in[14];
    const float* ln_b     = (const float*)d_in[15];
    const float* gate_w1  = (const float*)d_in[16];
    const float* gate_b1  = (const float*)d_in[17];
    const float* gate_w2  = (const float*)d_in[18];
    const float* gate_b2  = (const float*)d_in[19];
    const float* ro_w1    = (const float*)d_in[20];
    const float* ro_b1    = (const float*)d_in[21];
    const float* ro_w2    = (const float*)d_in[22];
    const float* ro_b2    = (const float*)d_in[23];
    float* out = (float*)d_out;

    const int N = in_sizes[0] / 42;       // 10000
    const int E = in_sizes[1] / 12;       // 160000
    const int B = out_size / DD;          // 16

    // workspace carve-up
    char* p = (char*)d_ws;
    auto alloc = [&](size_t bytes) {
        char* r = p;
        p += (bytes + 255) & ~(size_t)255;
        return (void*)r;
    };
    float*  h       = (float*)alloc((size_t)N * DD * 4);
    __bf16* hbf     = (__bf16*)alloc((size_t)N * DD * 2);
    float*  xh      = (float*)alloc((size_t)N * DD * 4);
    float*  a_s     = (float*)alloc((size_t)N * HH * 4);
    float*  a_d     = (float*)alloc((size_t)N * HH * 4);
    float*  a_e_all = (float*)alloc((size_t)(E + N) * LH * 4);  // [e][l*4+h]
    float*  wproj   = (float*)alloc((size_t)DD * LH * 4);
    float*  wpack   = (float*)alloc((size_t)DD * 36 * 4);
    __bf16* wf      = (__bf16*)alloc((size_t)6 * DD * DD * 2);  // swizzled bf16 weights
    float*  gate    = (float*)alloc((size_t)N * 4);
    float*  g_embed = (float*)alloc((size_t)B * DD * 4);
    float*  gmax    = (float*)alloc((size_t)B * 4);
    float*  gden    = (float*)alloc((size_t)B * 4);
    float*  wgt     = (float*)alloc((size_t)N * 4);
    int* deg        = (int*)alloc((size_t)N * 4);
    int* row_ptr    = (int*)alloc((size_t)(N + 1) * 4);
    int* cursor     = (int*)alloc((size_t)N * 4);
    int* csr_src    = (int*)alloc((size_t)E * 4);
    int* csr_eid    = (int*)alloc((size_t)E * 4);
    int* bstart     = (int*)alloc((size_t)(B + 1) * 4);

    const int* src_arr = edge_idx;
    const int* dst_arr = edge_idx + E;

    hipMemsetAsync(deg, 0, (size_t)N * 4, stream);
    hipMemsetAsync(g_embed, 0, (size_t)B * DD * 4, stream);
    hipMemsetAsync(gate, 0, (size_t)N * 4, stream);

    wproj_kernel<<<LL, 256, 0, stream>>>(gat_ew, att_edge, wproj);
    wpack_kernel<<<1, 256, 0, stream>>>(eenc_w, eenc_b, wproj, wpack);
    wswizzle_kernel<<<192, 256, 0, stream>>>(gat_w, gate_w1, wf);
    encoder_kernel<<<N, 256, 0, stream>>>(x, enc_w, enc_b, h, hbf, N);
    deg_kernel<<<(E + 255) / 256, 256, 0, stream>>>(dst_arr, deg, E);
    scan_kernel<<<1, 1024, 0, stream>>>(deg, row_ptr, N);
    copy_int_kernel<<<(N + 255) / 256, 256, 0, stream>>>(row_ptr, cursor, N);
    scatter_kernel<<<(E + 255) / 256, 256, 0, stream>>>(
        src_arr, dst_arr, cursor, csr_src, csr_eid, E);
    edge_pre_kernel<<<(E + 255) / 256, 256, 0, stream>>>(
        edge_attr, wpack, a_e_all, E);
    self_ae_kernel<<<(N * LH + 255) / 256, 256, 0, stream>>>(
        row_ptr, csr_eid, a_e_all, N, E);

    dim3 ggrid((N + 63) / 64, 4);
    for (int l = 0; l < LL; ++l) {
        gemm_mfma_kernel<<<ggrid, 256, 0, stream>>>(
            hbf, wf + (size_t)l * DD * DD, xh, N,
            att_src + l * DD, att_dst + l * DD, a_s, a_d,
            nullptr, nullptr, nullptr, nullptr);
        gat_message3_kernel<<<N, 256, 0, stream>>>(
            xh, a_s, a_d, a_e_all + l * HH, row_ptr, csr_src, csr_eid,
            gat_b + l * DD, ln_g + l * DD, ln_b + l * DD, h, hbf, N, E);
    }

    // pooling gate: gate[n] = relu(h@gate_w1+b1) . gate_w2 + b2, fused MFMA
    gemm_mfma_kernel<<<ggrid, 256, 0, stream>>>(
        hbf, wf + (size_t)5 * DD * DD, nullptr, N,
        nullptr, nullptr, nullptr, nullptr,
        gate_b1, gate_w2, gate_b2, gate);
    bstart_kernel<<<1, 32, 0, stream>>>(batch, bstart, N, B);
    gseg_kernel<<<B, 256, 0, stream>>>(gate, bstart, gmax, gden);
    wgt_kernel<<<(N + 255) / 256, 256, 0, stream>>>(gate, batch, gmax, gden, wgt, N);
    pool_scatter_kernel<<<(N + POOL_CHUNK - 1) / POOL_CHUNK, 256, 0, stream>>>(
        h, wgt, batch, g_embed, N);
    readout_kernel<<<B, 256, 0, stream>>>(g_embed, ro_w1, ro_b1, ro_w2, ro_b2, out);
}

// Round 11
// 517.815 us; speedup vs baseline: 1.2786x; 1.1046x over previous
//
#include <hip/hip_runtime.h>
#include <math.h>

// Problem constants (fixed-shape problem)
#define DD 256
#define HH 4
#define CC 64
#define LL 5
#define NEG_SLOPE 0.2f
#define LH 20   // L*H
#define WCAP 192  // per-wave LDS softmax-weight cache (deg ~ Poisson(16), max ~45)

typedef __bf16 bf16x8 __attribute__((ext_vector_type(8)));
typedef __bf16 bf16x4 __attribute__((ext_vector_type(4)));
typedef float f32x4 __attribute__((ext_vector_type(4)));

static __device__ __forceinline__ float lrelu(float x) {
    return x > 0.0f ? x : NEG_SLOPE * x;
}

// ---------------------------------------------------------------------------
// K0: wproj[k][l*4+h] = sum_c gat_ew[l][k][h*64+c] * att_edge[l][h][c]
__global__ __launch_bounds__(256) void wproj_kernel(
    const float* __restrict__ gat_ew, const float* __restrict__ att_edge,
    float* __restrict__ wproj) {
    int l = blockIdx.x;
    int k = threadIdx.x;
    const float* W = gat_ew + (size_t)l * DD * DD;
    const float* att = att_edge + l * DD;  // [H][C] flat = 256
    for (int hh = 0; hh < HH; ++hh) {
        float s = 0.f;
        #pragma unroll
        for (int c = 0; c < CC; ++c)
            s += W[k * DD + hh * CC + c] * att[hh * CC + c];
        wproj[k * LH + l * HH + hh] = s;
    }
}

// K0b: pack per-k weights: wpack[k][0..11]=Wt row, [12..31]=wproj row, [32]=eenc_b
__global__ __launch_bounds__(256) void wpack_kernel(
    const float* __restrict__ eenc_w, const float* __restrict__ eenc_b,
    const float* __restrict__ wproj, float* __restrict__ wpack) {
    int k = threadIdx.x;
    #pragma unroll
    for (int f = 0; f < 12; ++f) wpack[k * 36 + f] = eenc_w[f * 256 + k];
    #pragma unroll
    for (int j = 0; j < 20; ++j) wpack[k * 36 + 12 + j] = wproj[k * LH + j];
    wpack[k * 36 + 32] = eenc_b[k];
    wpack[k * 36 + 33] = 0.f; wpack[k * 36 + 34] = 0.f; wpack[k * 36 + 35] = 0.f;
}

// K0c: swizzle GEMM weights into MFMA B-fragment order, bf16.
// l in 0..4 = gat_w layers; l = 5 = gate_w1.
__global__ __launch_bounds__(256) void wswizzle_kernel(
    const float* __restrict__ gat_w, const float* __restrict__ gate_w1,
    __bf16* __restrict__ wf) {
    int b = blockIdx.x;           // l*32 + y*8 + ks
    int l = b >> 5;
    int rem = b & 31;
    int y = rem >> 3, ks = rem & 7;
    int tid = threadIdx.x;
    int t = tid >> 6, lane = tid & 63;
    int q = lane >> 4, r15 = lane & 15;
    const float* W = (l < 5) ? (gat_w + (size_t)l * DD * DD) : gate_w1;
    size_t obase = (((size_t)b * 4 + t) * 64 + lane) * 8;
    int kbase = ks * 32 + q * 8;
    int col = y * 64 + t * 16 + r15;
    #pragma unroll
    for (int j = 0; j < 8; ++j)
        wf[obase + j] = (__bf16)W[(size_t)(kbase + j) * DD + col];
}

// ---------------------------------------------------------------------------
// K1: node encoder h = relu(x @ enc_w + enc_b); also writes bf16 shadow
__global__ __launch_bounds__(256) void encoder_kernel(
    const float* __restrict__ x, const float* __restrict__ enc_w,
    const float* __restrict__ enc_b, float* __restrict__ h,
    __bf16* __restrict__ hbf, int N) {
    int n = blockIdx.x;
    int tid = threadIdx.x;
    __shared__ float xs[42];
    if (tid < 42) xs[tid] = x[(size_t)n * 42 + tid];
    __syncthreads();
    float acc = enc_b[tid];
    #pragma unroll
    for (int f = 0; f < 42; ++f) acc += xs[f] * enc_w[f * DD + tid];
    float v = fmaxf(acc, 0.f);
    h[(size_t)n * DD + tid] = v;
    hbf[(size_t)n * DD + tid] = (__bf16)v;
}

// ---------------------------------------------------------------------------
// K2: per-edge a_e (R7 form — compiler-scheduled).
__global__ __launch_bounds__(256) void edge_pre_kernel(
    const float* __restrict__ edge_attr, const float* __restrict__ wpack,
    float* __restrict__ a_e_all, int E) {
    int tid = threadIdx.x;
    int e = blockIdx.x * 256 + tid;
    bool v = e < E;
    float ea[12] = {};
    if (v) {
        const float4* p = (const float4*)(edge_attr + (size_t)e * 12);
        *(float4*)&ea[0] = p[0]; *(float4*)&ea[4] = p[1]; *(float4*)&ea[8] = p[2];
    }
    float4 acc[5];
    #pragma unroll
    for (int q = 0; q < 5; ++q) acc[q] = make_float4(0.f, 0.f, 0.f, 0.f);
    for (int k = 0; k < 256; ++k) {
        const float4* wp = (const float4*)(wpack + k * 36);
        float4 wa = wp[0], wb = wp[1], wc = wp[2];
        float4 wt = wp[8];  // .x = bias
        float m0 = wt.x;
        m0 += ea[0] * wa.x + ea[1] * wa.y + ea[2] * wa.z + ea[3] * wa.w
            + ea[4] * wb.x + ea[5] * wb.y + ea[6] * wb.z + ea[7] * wb.w
            + ea[8] * wc.x + ea[9] * wc.y + ea[10] * wc.z + ea[11] * wc.w;
        m0 = fmaxf(m0, 0.f);
        float4 p0 = wp[3], p1 = wp[4], p2 = wp[5], p3 = wp[6], p4 = wp[7];
        acc[0].x += m0 * p0.x; acc[0].y += m0 * p0.y; acc[0].z += m0 * p0.z; acc[0].w += m0 * p0.w;
        acc[1].x += m0 * p1.x; acc[1].y += m0 * p1.y; acc[1].z += m0 * p1.z; acc[1].w += m0 * p1.w;
        acc[2].x += m0 * p2.x; acc[2].y += m0 * p2.y; acc[2].z += m0 * p2.z; acc[2].w += m0 * p2.w;
        acc[3].x += m0 * p3.x; acc[3].y += m0 * p3.y; acc[3].z += m0 * p3.z; acc[3].w += m0 * p3.w;
        acc[4].x += m0 * p4.x; acc[4].y += m0 * p4.y; acc[4].z += m0 * p4.z; acc[4].w += m0 * p4.w;
    }
    if (v) {
        float4* o = (float4*)(a_e_all + (size_t)e * LH);
        #pragma unroll
        for (int q = 0; q < 5; ++q) o[q] = acc[q];
    }
}

// ---------------------------------------------------------------------------
__global__ void deg_kernel(const int* __restrict__ dst, int* __restrict__ deg, int E) {
    int e = blockIdx.x * 256 + threadIdx.x;
    if (e < E) atomicAdd(&deg[dst[e]], 1);
}

__global__ void self_ae_kernel(const int* __restrict__ row_ptr,
                               const int* __restrict__ csr_eid,
                               float* __restrict__ a_e_all, int N, int E) {
    int i = blockIdx.x * 256 + threadIdx.x;
    if (i >= N * LH) return;
    int n = i / LH;
    int j = i % LH;
    int rs = row_ptr[n], re = row_ptr[n + 1];
    float s = 0.f;
    for (int k = rs; k < re; ++k)
        s += a_e_all[(size_t)csr_eid[k] * LH + j];
    a_e_all[(size_t)(E + n) * LH + j] = s / (float)max(re - rs, 1);
}

__global__ __launch_bounds__(1024) void scan_kernel(const int* __restrict__ deg,
                                                    int* __restrict__ row_ptr, int n) {
    __shared__ int buf[1024];
    __shared__ int carry_s;
    int tid = threadIdx.x;
    if (tid == 0) carry_s = 0;
    __syncthreads();
    for (int base = 0; base < n; base += 1024) {
        int i = base + tid;
        int v = (i < n) ? deg[i] : 0;
        buf[tid] = v;
        __syncthreads();
        for (int off = 1; off < 1024; off <<= 1) {
            int t = (tid >= off) ? buf[tid - off] : 0;
            __syncthreads();
            buf[tid] += t;
            __syncthreads();
        }
        int carry = carry_s;
        if (i < n) row_ptr[i] = carry + buf[tid] - v;
        __syncthreads();
        if (tid == 1023) carry_s = carry + buf[1023];
        __syncthreads();
    }
    if (tid == 0) row_ptr[n] = carry_s;
}

__global__ void copy_int_kernel(const int* __restrict__ a, int* __restrict__ b, int n) {
    int i = blockIdx.x * 256 + threadIdx.x;
    if (i < n) b[i] = a[i];
}

__global__ void scatter_kernel(const int* __restrict__ src, const int* __restrict__ dst,
                               int* __restrict__ cursor, int* __restrict__ csr_src,
                               int* __restrict__ csr_eid, int E) {
    int e = blockIdx.x * 256 + threadIdx.x;
    if (e >= E) return;
    int d = dst[e];
    int pos = atomicAdd(&cursor[d], 1);
    csr_src[pos] = src[e];
    csr_eid[pos] = e;
}

// ---------------------------------------------------------------------------
// MFMA GEMM: xh[M,256] = hbf @ W (bf16 in, fp32 acc). 64x64 tile per block,
// blockIdx.y = column quarter == head. No LDS/barriers. Fused epilogues.
__global__ __launch_bounds__(256) void gemm_mfma_kernel(
    const __bf16* __restrict__ hbf, const __bf16* __restrict__ wf,
    float* __restrict__ xh, int M,
    const float* __restrict__ att_src, const float* __restrict__ att_dst,
    float* __restrict__ a_s, float* __restrict__ a_d,
    const float* __restrict__ bias, const float* __restrict__ gate_w2,
    const float* __restrict__ gate_b2, float* __restrict__ gate_out) {
    int tid = threadIdx.x;
    int w = tid >> 6, lane = tid & 63;
    int q = lane >> 4, r15 = lane & 15;
    int m0 = blockIdx.x * 64;
    int y = blockIdx.y;
    int arow = m0 + w * 16 + r15;
    int arowc = min(arow, M - 1);
    const __bf16* ap = hbf + (size_t)arowc * DD + q * 8;
    const bf16x8* bp0 = (const bf16x8*)wf + (size_t)(y * 8) * 4 * 64 + lane;
    f32x4 acc[4];
    #pragma unroll
    for (int t = 0; t < 4; ++t) acc[t] = (f32x4){0.f, 0.f, 0.f, 0.f};
    #pragma unroll
    for (int ks = 0; ks < 8; ++ks) {
        bf16x8 a = *(const bf16x8*)(ap + ks * 32);
        const bf16x8* bp = bp0 + (size_t)ks * 4 * 64;
        #pragma unroll
        for (int t = 0; t < 4; ++t) {
            bf16x8 b = bp[(size_t)t * 64];
            acc[t] = __builtin_amdgcn_mfma_f32_16x16x32_bf16(a, b, acc[t], 0, 0, 0);
        }
    }
    if (xh) {
        #pragma unroll
        for (int t = 0; t < 4; ++t) {
            int col = y * 64 + t * 16 + r15;
            #pragma unroll
            for (int r = 0; r < 4; ++r) {
                int rc = m0 + w * 16 + q * 4 + r;
                if (rc < M) xh[(size_t)rc * DD + col] = acc[t][r];
            }
        }
    }
    if (att_src) {
        #pragma unroll
        for (int r = 0; r < 4; ++r) {
            float ps = 0.f, pd = 0.f;
            #pragma unroll
            for (int t = 0; t < 4; ++t) {
                int col = y * 64 + t * 16 + r15;
                ps += acc[t][r] * att_src[col];
                pd += acc[t][r] * att_dst[col];
            }
            #pragma unroll
            for (int mask = 1; mask < 16; mask <<= 1) {
                ps += __shfl_xor(ps, mask, 64);
                pd += __shfl_xor(pd, mask, 64);
            }
            int rc = m0 + w * 16 + q * 4 + r;
            if (r15 == 0 && rc < M) {
                a_s[rc * HH + y] = ps;
                a_d[rc * HH + y] = pd;
            }
        }
    }
    if (gate_w2) {
        #pragma unroll
        for (int r = 0; r < 4; ++r) {
            float pg = 0.f;
            #pragma unroll
            for (int t = 0; t < 4; ++t) {
                int col = y * 64 + t * 16 + r15;
                pg += fmaxf(acc[t][r] + bias[col], 0.f) * gate_w2[col];
            }
            #pragma unroll
            for (int mask = 1; mask < 16; mask <<= 1) pg += __shfl_xor(pg, mask, 64);
            int rc = m0 + w * 16 + q * 4 + r;
            if (r15 == 0 && rc < M) {
                float add = pg + (y == 0 ? gate_b2[0] : 0.f);
                atomicAdd(&gate_out[rc], add);
            }
        }
    }
}

// ---------------------------------------------------------------------------
// K6 v4: WAVE-PER-NODE fused alpha + softmax + aggregation + LN + residual.
// 4 nodes/block; lane = (head = lane>>4, j = lane&15). Pass 1: all 64 lanes
// active (16 edges x 4 heads at once); per-head softmax state reduced with 4
// shuffles in the aligned 16-lane group. Weights cached in wave-private LDS
// [kk*4+h] (2-way write / broadcast read; same-wave LDS is ordered -> NO
// barriers anywhere). Pass 3: xh rows read as float4/lane (1KB/wave). LN via
// wave shuffle reduction. Maintains bf16 shadow of h.
__global__ __launch_bounds__(256) void gat_message4_kernel(
    const float* __restrict__ xh, const float* __restrict__ a_s,
    const float* __restrict__ a_d, const float* __restrict__ a_e,  // + l*4; [e][20]
    const int* __restrict__ row_ptr, const int* __restrict__ csr_src,
    const int* __restrict__ csr_eid, const float* __restrict__ gat_b,
    const float* __restrict__ ln_g, const float* __restrict__ ln_b,
    float* __restrict__ h, __bf16* __restrict__ hbf, int N, int E) {
    __shared__ float lws[4][WCAP * 4];   // 12 KB: [wave][kk*4 + head]
    int tid = threadIdx.x;
    int w = tid >> 6, lane = tid & 63;
    int n = blockIdx.x * 4 + w;
    if (n >= N) return;
    int hh = lane >> 4, j = lane & 15;
    int rs = row_ptr[n], re = row_ptr[n + 1];
    int deg = re - rs;
    float adn = a_d[n * HH + hh];
    float al_self = lrelu(a_s[n * HH + hh] + adn + a_e[(size_t)(E + n) * LH + hh]);
    // pass 1: lane handles edges rs+j, rs+j+16, ... for its head; online max+den
    float m = al_self, den = 0.f;
    for (int k = rs + j; k < re; k += 16) {
        int kk = k - rs;
        int s = csr_src[k];
        int eid = csr_eid[k];
        float a = lrelu(a_s[s * HH + hh] + adn + a_e[(size_t)eid * LH + hh]);
        if (kk < WCAP) lws[w][kk * 4 + hh] = a;
        float mn = fmaxf(m, a);
        den = den * __expf(m - mn) + __expf(a - mn);
        m = mn;
    }
    // reduce softmax state within the 16-lane head group
    #pragma unroll
    for (int off = 1; off < 16; off <<= 1) {
        float m2 = __shfl_xor(m, off, 64);
        float d2 = __shfl_xor(den, off, 64);
        float mn = fmaxf(m, m2);
        den = den * __expf(m - mn) + d2 * __expf(m2 - mn);
        m = mn;
    }
    den += __expf(al_self - m);
    float inv_den = 1.0f / den;
    // convert cached alpha -> weight (same lanes rewrite their own entries)
    int cap = min(deg, WCAP);
    for (int kk = j; kk < cap; kk += 16)
        lws[w][kk * 4 + hh] = __expf(lws[w][kk * 4 + hh] - m) * inv_den;
    // pass 3: aggregation; lane owns dims [lane*4, lane*4+4) (head == lane>>4)
    float wself = __expf(al_self - m) * inv_den;
    const float4* xrow = (const float4*)(xh + (size_t)n * DD) + lane;
    float4 xs = *xrow;
    float4 acc;
    acc.x = wself * xs.x; acc.y = wself * xs.y;
    acc.z = wself * xs.z; acc.w = wself * xs.w;
    for (int k = rs; k < re; ++k) {
        int kk = k - rs;
        int s = csr_src[k];
        float wgt;
        if (kk < WCAP) wgt = lws[w][kk * 4 + hh];
        else {
            float a = lrelu(a_s[s * HH + hh] + adn + a_e[(size_t)csr_eid[k] * LH + hh]);
            wgt = __expf(a - m) * inv_den;
        }
        float4 xr = *((const float4*)(xh + (size_t)s * DD) + lane);
        acc.x += wgt * xr.x; acc.y += wgt * xr.y;
        acc.z += wgt * xr.z; acc.w += wgt * xr.w;
    }
    float4 gb = *((const float4*)gat_b + lane);
    float4 val;
    val.x = acc.x + gb.x; val.y = acc.y + gb.y;
    val.z = acc.z + gb.z; val.w = acc.w + gb.w;
    // LN over 256 dims: wave shuffle reduction
    float s1 = val.x + val.y + val.z + val.w;
    float s2 = val.x * val.x + val.y * val.y + val.z * val.z + val.w * val.w;
    #pragma unroll
    for (int off = 1; off < 64; off <<= 1) {
        s1 += __shfl_xor(s1, off, 64);
        s2 += __shfl_xor(s2, off, 64);
    }
    float mu = s1 * (1.0f / DD);
    float var = s2 * (1.0f / DD) - mu * mu;
    float rstd = rsqrtf(var + 1e-5f);
    float4 lg = *((const float4*)ln_g + lane);
    float4 lb = *((const float4*)ln_b + lane);
    float4 nv;
    nv.x = fmaxf((val.x - mu) * rstd * lg.x + lb.x, 0.f);
    nv.y = fmaxf((val.y - mu) * rstd * lg.y + lb.y, 0.f);
    nv.z = fmaxf((val.z - mu) * rstd * lg.z + lb.z, 0.f);
    nv.w = fmaxf((val.w - mu) * rstd * lg.w + lb.w, 0.f);
    float4* hp = (float4*)(h + (size_t)n * DD) + lane;
    float4 hv = *hp;
    hv.x += nv.x; hv.y += nv.y; hv.z += nv.z; hv.w += nv.w;
    *hp = hv;
    bf16x4 hb;
    hb[0] = (__bf16)hv.x; hb[1] = (__bf16)hv.y;
    hb[2] = (__bf16)hv.z; hb[3] = (__bf16)hv.w;
    *((bf16x4*)(hbf + (size_t)n * DD) + lane) = hb;
}

// ---------------------------------------------------------------------------
__global__ void bstart_kernel(const int* __restrict__ batch, int* __restrict__ bstart,
                              int N, int B) {
    int b = threadIdx.x;
    if (b > B) return;
    int lo = 0, hi = N;
    while (lo < hi) {
        int mid = (lo + hi) >> 1;
        if (batch[mid] < b) lo = mid + 1; else hi = mid;
    }
    bstart[b] = lo;
}

__global__ __launch_bounds__(256) void gseg_kernel(
    const float* __restrict__ gate, const int* __restrict__ bstart,
    float* __restrict__ gmax, float* __restrict__ gden) {
    int b = blockIdx.x;
    int tid = threadIdx.x;
    int s0 = bstart[b], s1 = bstart[b + 1];
    __shared__ float red[256];
    float m = -1e30f;
    for (int i = s0 + tid; i < s1; i += 256) m = fmaxf(m, gate[i]);
    red[tid] = m;
    __syncthreads();
    for (int off = 128; off; off >>= 1) {
        if (tid < off) red[tid] = fmaxf(red[tid], red[tid + off]);
        __syncthreads();
    }
    float gm = red[0];
    __syncthreads();
    float s = 0.f;
    for (int i = s0 + tid; i < s1; i += 256) s += __expf(gate[i] - gm);
    red[tid] = s;
    __syncthreads();
    for (int off = 128; off; off >>= 1) {
        if (tid < off) red[tid] += red[tid + off];
        __syncthreads();
    }
    if (tid == 0) {
        gmax[b] = gm;
        gden[b] = red[0];
    }
}

__global__ void wgt_kernel(const float* __restrict__ gate, const int* __restrict__ batch,
                           const float* __restrict__ gmax, const float* __restrict__ gden,
                           float* __restrict__ wgt, int N) {
    int n = blockIdx.x * 256 + threadIdx.x;
    if (n >= N) return;
    int b = batch[n];
    wgt[n] = __expf(gate[n] - gmax[b]) / gden[b];
}

#define POOL_CHUNK 32
__global__ __launch_bounds__(256) void pool_scatter_kernel(
    const float* __restrict__ h, const float* __restrict__ wgt,
    const int* __restrict__ batch, float* __restrict__ g_embed, int N) {
    int i0 = blockIdx.x * POOL_CHUNK;
    int d = threadIdx.x;
    int iend = min(i0 + POOL_CHUNK, N);
    float acc = 0.f;
    int cur = batch[i0];
    for (int i = i0; i < iend; ++i) {
        int b = batch[i];
        if (b != cur) {
            atomicAdd(&g_embed[cur * DD + d], acc);
            acc = 0.f;
            cur = b;
        }
        acc += wgt[i] * h[(size_t)i * DD + d];
    }
    atomicAdd(&g_embed[cur * DD + d], acc);
}

__global__ __launch_bounds__(256) void readout_kernel(
    const float* __restrict__ g_embed, const float* __restrict__ w1,
    const float* __restrict__ b1, const float* __restrict__ w2,
    const float* __restrict__ b2, float* __restrict__ out) {
    int b = blockIdx.x;
    int tid = threadIdx.x;
    __shared__ float gvec[256];
    __shared__ float hid[256];
    gvec[tid] = g_embed[b * DD + tid];
    __syncthreads();
    float hv = b1[tid];
    for (int k = 0; k < DD; ++k) hv += gvec[k] * w1[k * DD + tid];
    hid[tid] = fmaxf(hv, 0.f);
    __syncthreads();
    float o = b2[tid];
    for (int t = 0; t < DD; ++t) o += hid[t] * w2[t * DD + tid];
    out[b * DD + tid] = o;
}

// ---------------------------------------------------------------------------
extern "C" void kernel_launch(void* const* d_in, const int* in_sizes, int n_in,
                              void* d_out, int out_size, void* d_ws, size_t ws_size,
                              hipStream_t stream) {
    const float* x        = (const float*)d_in[0];
    const float* edge_attr= (const float*)d_in[1];
    const int*   edge_idx = (const int*)d_in[2];
    const int*   batch    = (const int*)d_in[3];
    const float* enc_w    = (const float*)d_in[4];
    const float* enc_b    = (const float*)d_in[5];
    const float* eenc_w   = (const float*)d_in[6];
    const float* eenc_b   = (const float*)d_in[7];
    const float* gat_w    = (const float*)d_in[8];
    const float* att_src  = (const float*)d_in[9];
    const float* att_dst  = (const float*)d_in[10];
    const float* att_edge = (const float*)d_in[11];
    const float* gat_ew   = (const float*)d_in[12];
    const float* gat_b    = (const float*)d_in[13];
    const float* ln_g     = (const float*)d_in[14];
    const float* ln_b     = (const float*)d_in[15];
    const float* gate_w1  = (const float*)d_in[16];
    const float* gate_b1  = (const float*)d_in[17];
    const float* gate_w2  = (const float*)d_in[18];
    const float* gate_b2  = (const float*)d_in[19];
    const float* ro_w1    = (const float*)d_in[20];
    const float* ro_b1    = (const float*)d_in[21];
    const float* ro_w2    = (const float*)d_in[22];
    const float* ro_b2    = (const float*)d_in[23];
    float* out = (float*)d_out;

    const int N = in_sizes[0] / 42;       // 10000
    const int E = in_sizes[1] / 12;       // 160000
    const int B = out_size / DD;          // 16

    // workspace carve-up
    char* p = (char*)d_ws;
    auto alloc = [&](size_t bytes) {
        char* r = p;
        p += (bytes + 255) & ~(size_t)255;
        return (void*)r;
    };
    float*  h       = (float*)alloc((size_t)N * DD * 4);
    __bf16* hbf     = (__bf16*)alloc((size_t)N * DD * 2);
    float*  xh      = (float*)alloc((size_t)N * DD * 4);
    float*  a_s     = (float*)alloc((size_t)N * HH * 4);
    float*  a_d     = (float*)alloc((size_t)N * HH * 4);
    float*  a_e_all = (float*)alloc((size_t)(E + N) * LH * 4);  // [e][l*4+h]
    float*  wproj   = (float*)alloc((size_t)DD * LH * 4);
    float*  wpack   = (float*)alloc((size_t)DD * 36 * 4);
    __bf16* wf      = (__bf16*)alloc((size_t)6 * DD * DD * 2);  // swizzled bf16 weights
    float*  gate    = (float*)alloc((size_t)N * 4);
    float*  g_embed = (float*)alloc((size_t)B * DD * 4);
    float*  gmax    = (float*)alloc((size_t)B * 4);
    float*  gden    = (float*)alloc((size_t)B * 4);
    float*  wgt     = (float*)alloc((size_t)N * 4);
    int* deg        = (int*)alloc((size_t)N * 4);
    int* row_ptr    = (int*)alloc((size_t)(N + 1) * 4);
    int* cursor     = (int*)alloc((size_t)N * 4);
    int* csr_src    = (int*)alloc((size_t)E * 4);
    int* csr_eid    = (int*)alloc((size_t)E * 4);
    int* bstart     = (int*)alloc((size_t)(B + 1) * 4);

    const int* src_arr = edge_idx;
    const int* dst_arr = edge_idx + E;

    hipMemsetAsync(deg, 0, (size_t)N * 4, stream);
    hipMemsetAsync(g_embed, 0, (size_t)B * DD * 4, stream);
    hipMemsetAsync(gate, 0, (size_t)N * 4, stream);

    wproj_kernel<<<LL, 256, 0, stream>>>(gat_ew, att_edge, wproj);
    wpack_kernel<<<1, 256, 0, stream>>>(eenc_w, eenc_b, wproj, wpack);
    wswizzle_kernel<<<192, 256, 0, stream>>>(gat_w, gate_w1, wf);
    encoder_kernel<<<N, 256, 0, stream>>>(x, enc_w, enc_b, h, hbf, N);
    deg_kernel<<<(E + 255) / 256, 256, 0, stream>>>(dst_arr, deg, E);
    scan_kernel<<<1, 1024, 0, stream>>>(deg, row_ptr, N);
    copy_int_kernel<<<(N + 255) / 256, 256, 0, stream>>>(row_ptr, cursor, N);
    scatter_kernel<<<(E + 255) / 256, 256, 0, stream>>>(
        src_arr, dst_arr, cursor, csr_src, csr_eid, E);
    edge_pre_kernel<<<(E + 255) / 256, 256, 0, stream>>>(
        edge_attr, wpack, a_e_all, E);
    self_ae_kernel<<<(N * LH + 255) / 256, 256, 0, stream>>>(
        row_ptr, csr_eid, a_e_all, N, E);

    dim3 ggrid((N + 63) / 64, 4);
    for (int l = 0; l < LL; ++l) {
        gemm_mfma_kernel<<<ggrid, 256, 0, stream>>>(
            hbf, wf + (size_t)l * DD * DD, xh, N,
            att_src + l * DD, att_dst + l * DD, a_s, a_d,
            nullptr, nullptr, nullptr, nullptr);
        gat_message4_kernel<<<(N + 3) / 4, 256, 0, stream>>>(
            xh, a_s, a_d, a_e_all + l * HH, row_ptr, csr_src, csr_eid,
            gat_b + l * DD, ln_g + l * DD, ln_b + l * DD, h, hbf, N, E);
    }

    // pooling gate: gate[n] = relu(h@gate_w1+b1) . gate_w2 + b2, fused MFMA
    gemm_mfma_kernel<<<ggrid, 256, 0, stream>>>(
        hbf, wf + (size_t)5 * DD * DD, nullptr, N,
        nullptr, nullptr, nullptr, nullptr,
        gate_b1, gate_w2, gate_b2, gate);
    bstart_kernel<<<1, 32, 0, stream>>>(batch, bstart, N, B);
    gseg_kernel<<<B, 256, 0, stream>>>(gate, bstart, gmax, gden);
    wgt_kernel<<<(N + 255) / 256, 256, 0, stream>>>(gate, batch, gmax, gden, wgt, N);
    pool_scatter_kernel<<<(N + POOL_CHUNK - 1) / POOL_CHUNK, 256, 0, stream>>>(
        h, wgt, batch, g_embed, N);
    readout_kernel<<<B, 256, 0, stream>>>(g_embed, ro_w1, ro_b1, ro_w2, ro_b2, out);
}

// Round 12
// 494.756 us; speedup vs baseline: 1.3381x; 1.0466x over previous
//
#include <hip/hip_runtime.h>
#include <math.h>

// Problem constants (fixed-shape problem)
#define DD 256
#define HH 4
#define CC 64
#define LL 5
#define NEG_SLOPE 0.2f
#define LH 20   // L*H
#define WCAP 192  // per-wave LDS softmax-weight cache

typedef __bf16 bf16x8 __attribute__((ext_vector_type(8)));
typedef __bf16 bf16x4 __attribute__((ext_vector_type(4)));
typedef float f32x4 __attribute__((ext_vector_type(4)));

static __device__ __forceinline__ float lrelu(float x) {
    return x > 0.0f ? x : NEG_SLOPE * x;
}

// ---------------------------------------------------------------------------
// K0: wproj[k][l*4+h] = sum_c gat_ew[l][k][h*64+c] * att_edge[l][h][c]
__global__ __launch_bounds__(256) void wproj_kernel(
    const float* __restrict__ gat_ew, const float* __restrict__ att_edge,
    float* __restrict__ wproj) {
    int l = blockIdx.x;
    int k = threadIdx.x;
    const float* W = gat_ew + (size_t)l * DD * DD;
    const float* att = att_edge + l * DD;  // [H][C] flat = 256
    for (int hh = 0; hh < HH; ++hh) {
        float s = 0.f;
        #pragma unroll
        for (int c = 0; c < CC; ++c)
            s += W[k * DD + hh * CC + c] * att[hh * CC + c];
        wproj[k * LH + l * HH + hh] = s;
    }
}

// K0b: pack edge-encoder + wproj weights into MFMA B-fragment order (bf16).
// wfe: 16 col-tiles of eenc_w [K=32 pad: k<12 real, k==12 = eenc_b (bias as
// extra K-row, A supplies 1.0), k>12 zero]. wfp: 8 ks x 2 col-tiles of wproj
// [256 x 32 pad, col<20 real].
__global__ __launch_bounds__(256) void pack_edge_frags_kernel(
    const float* __restrict__ eenc_w, const float* __restrict__ eenc_b,
    const float* __restrict__ wproj, __bf16* __restrict__ wfe,
    __bf16* __restrict__ wfp) {
    int tid = threadIdx.x;
    for (int idx = tid; idx < 16 * 64; idx += 256) {
        int t = idx >> 6, lane = idx & 63;
        int q = lane >> 4, r15 = lane & 15;
        int col = t * 16 + r15;
        #pragma unroll
        for (int j = 0; j < 8; ++j) {
            int k = q * 8 + j;
            float v = (k < 12) ? eenc_w[k * 256 + col]
                               : (k == 12 ? eenc_b[col] : 0.f);
            wfe[(size_t)idx * 8 + j] = (__bf16)v;
        }
    }
    for (int idx = tid; idx < 16 * 64; idx += 256) {
        int sidx = idx >> 6, lane = idx & 63;
        int s = sidx >> 1, t2 = sidx & 1;
        int q = lane >> 4, r15 = lane & 15;
        int col = t2 * 16 + r15;
        #pragma unroll
        for (int j = 0; j < 8; ++j) {
            int k = s * 32 + q * 8 + j;
            float v = (col < LH) ? wproj[k * LH + col] : 0.f;
            wfp[(size_t)idx * 8 + j] = (__bf16)v;
        }
    }
}

// ---------------------------------------------------------------------------
// K0c: swizzle GEMM weights into MFMA B-fragment order, bf16.
// l in 0..4 = gat_w layers; l = 5 = gate_w1.
__global__ __launch_bounds__(256) void wswizzle_kernel(
    const float* __restrict__ gat_w, const float* __restrict__ gate_w1,
    __bf16* __restrict__ wf) {
    int b = blockIdx.x;           // l*32 + y*8 + ks
    int l = b >> 5;
    int rem = b & 31;
    int y = rem >> 3, ks = rem & 7;
    int tid = threadIdx.x;
    int t = tid >> 6, lane = tid & 63;
    int q = lane >> 4, r15 = lane & 15;
    const float* W = (l < 5) ? (gat_w + (size_t)l * DD * DD) : gate_w1;
    size_t obase = (((size_t)b * 4 + t) * 64 + lane) * 8;
    int kbase = ks * 32 + q * 8;
    int col = y * 64 + t * 16 + r15;
    #pragma unroll
    for (int j = 0; j < 8; ++j)
        wf[obase + j] = (__bf16)W[(size_t)(kbase + j) * DD + col];
}

// ---------------------------------------------------------------------------
// K1: node encoder h = relu(x @ enc_w + enc_b); also writes bf16 shadow
__global__ __launch_bounds__(256) void encoder_kernel(
    const float* __restrict__ x, const float* __restrict__ enc_w,
    const float* __restrict__ enc_b, float* __restrict__ h,
    __bf16* __restrict__ hbf, int N) {
    int n = blockIdx.x;
    int tid = threadIdx.x;
    __shared__ float xs[42];
    if (tid < 42) xs[tid] = x[(size_t)n * 42 + tid];
    __syncthreads();
    float acc = enc_b[tid];
    #pragma unroll
    for (int f = 0; f < 42; ++f) acc += xs[f] * enc_w[f * DD + tid];
    float v = fmaxf(acc, 0.f);
    h[(size_t)n * DD + tid] = v;
    hbf[(size_t)n * DD + tid] = (__bf16)v;
}

// ---------------------------------------------------------------------------
// K2 v5: edge_pre on MATRIX CORES. Per wave: 16 edges.
// Stage A: X2[16x256] = relu(edge_attr[16x12] @ eenc_w + b) via 16 MFMAs
//   (K=32 pad; bias folded as K-row 12 with A=1.0). bf16 result staged in
//   wave-private LDS [16][264] (b16 scatter writes ~2-way = free; b128 reads).
// Stage B: a_e[16x20] = X2 @ wproj via 16 MFMAs (N=32 pad). No barriers.
__global__ __launch_bounds__(256) void edge_mfma_kernel(
    const float* __restrict__ edge_attr, const __bf16* __restrict__ wfe,
    const __bf16* __restrict__ wfp, float* __restrict__ a_e_all, int E) {
    __shared__ __bf16 sm[4][16][264];   // 33 KB
    int tid = threadIdx.x;
    int w = tid >> 6, lane = tid & 63;
    int q = lane >> 4, r15 = lane & 15;
    int eb = blockIdx.x * 64 + w * 16;
    // A1 fragment: m = r15 (edge), k = q*8+j
    int e = eb + r15;
    int ec = min(e, E - 1);
    bf16x8 a1;
    #pragma unroll
    for (int j = 0; j < 8; ++j) a1[j] = (__bf16)0.f;
    if (q == 0) {
        const float4* p = (const float4*)(edge_attr + (size_t)ec * 12);
        float4 p0 = p[0], p1 = p[1];
        a1[0] = (__bf16)p0.x; a1[1] = (__bf16)p0.y; a1[2] = (__bf16)p0.z; a1[3] = (__bf16)p0.w;
        a1[4] = (__bf16)p1.x; a1[5] = (__bf16)p1.y; a1[6] = (__bf16)p1.z; a1[7] = (__bf16)p1.w;
    } else if (q == 1) {
        float4 p2 = *(const float4*)(edge_attr + (size_t)ec * 12 + 8);
        a1[0] = (__bf16)p2.x; a1[1] = (__bf16)p2.y; a1[2] = (__bf16)p2.z; a1[3] = (__bf16)p2.w;
        a1[4] = (__bf16)1.0f;  // k = 12: bias row
    }
    // stage A: 16 col-tiles
    const bf16x8* wfeP = (const bf16x8*)wfe;
    f32x4 zero = (f32x4){0.f, 0.f, 0.f, 0.f};
    #pragma unroll
    for (int t = 0; t < 16; ++t) {
        bf16x8 bfr = wfeP[t * 64 + lane];
        f32x4 c = __builtin_amdgcn_mfma_f32_16x16x32_bf16(a1, bfr, zero, 0, 0, 0);
        int col = t * 16 + r15;
        #pragma unroll
        for (int r = 0; r < 4; ++r)
            sm[w][q * 4 + r][col] = (__bf16)fmaxf(c[r], 0.f);
    }
    // stage B: K=256 over 8 steps, 2 col-tiles (N pad 32)
    const bf16x8* wfpP = (const bf16x8*)wfp;
    f32x4 c2[2];
    c2[0] = zero; c2[1] = zero;
    #pragma unroll
    for (int s = 0; s < 8; ++s) {
        bf16x8 a2 = *(const bf16x8*)&sm[w][r15][s * 32 + q * 8];
        #pragma unroll
        for (int t2 = 0; t2 < 2; ++t2)
            c2[t2] = __builtin_amdgcn_mfma_f32_16x16x32_bf16(
                a2, wfpP[(s * 2 + t2) * 64 + lane], c2[t2], 0, 0, 0);
    }
    // write a_e: row = edge eb + q*4+r, col = t2*16 + r15 (keep < 20)
    #pragma unroll
    for (int t2 = 0; t2 < 2; ++t2) {
        int col = t2 * 16 + r15;
        if (col >= LH) continue;
        #pragma unroll
        for (int r = 0; r < 4; ++r) {
            int e2 = eb + q * 4 + r;
            if (e2 < E) a_e_all[(size_t)e2 * LH + col] = c2[t2][r];
        }
    }
}

// ---------------------------------------------------------------------------
__global__ void deg_kernel(const int* __restrict__ dst, int* __restrict__ deg, int E) {
    int e = blockIdx.x * 256 + threadIdx.x;
    if (e < E) atomicAdd(&deg[dst[e]], 1);
}

__global__ void self_ae_kernel(const int* __restrict__ row_ptr,
                               const int* __restrict__ csr_eid,
                               float* __restrict__ a_e_all, int N, int E) {
    int i = blockIdx.x * 256 + threadIdx.x;
    if (i >= N * LH) return;
    int n = i / LH;
    int j = i % LH;
    int rs = row_ptr[n], re = row_ptr[n + 1];
    float s = 0.f;
    for (int k = rs; k < re; ++k)
        s += a_e_all[(size_t)csr_eid[k] * LH + j];
    a_e_all[(size_t)(E + n) * LH + j] = s / (float)max(re - rs, 1);
}

__global__ __launch_bounds__(1024) void scan_kernel(const int* __restrict__ deg,
                                                    int* __restrict__ row_ptr, int n) {
    __shared__ int buf[1024];
    __shared__ int carry_s;
    int tid = threadIdx.x;
    if (tid == 0) carry_s = 0;
    __syncthreads();
    for (int base = 0; base < n; base += 1024) {
        int i = base + tid;
        int v = (i < n) ? deg[i] : 0;
        buf[tid] = v;
        __syncthreads();
        for (int off = 1; off < 1024; off <<= 1) {
            int t = (tid >= off) ? buf[tid - off] : 0;
            __syncthreads();
            buf[tid] += t;
            __syncthreads();
        }
        int carry = carry_s;
        if (i < n) row_ptr[i] = carry + buf[tid] - v;
        __syncthreads();
        if (tid == 1023) carry_s = carry + buf[1023];
        __syncthreads();
    }
    if (tid == 0) row_ptr[n] = carry_s;
}

__global__ void copy_int_kernel(const int* __restrict__ a, int* __restrict__ b, int n) {
    int i = blockIdx.x * 256 + threadIdx.x;
    if (i < n) b[i] = a[i];
}

__global__ void scatter_kernel(const int* __restrict__ src, const int* __restrict__ dst,
                               int* __restrict__ cursor, int* __restrict__ csr_src,
                               int* __restrict__ csr_eid, int E) {
    int e = blockIdx.x * 256 + threadIdx.x;
    if (e >= E) return;
    int d = dst[e];
    int pos = atomicAdd(&cursor[d], 1);
    csr_src[pos] = src[e];
    csr_eid[pos] = e;
}

// ---------------------------------------------------------------------------
// MFMA GEMM: xh[M,256] = hbf @ W (bf16 in, fp32 acc). 64x64 tile per block,
// blockIdx.y = column quarter == head. No LDS/barriers. Fused epilogues.
__global__ __launch_bounds__(256) void gemm_mfma_kernel(
    const __bf16* __restrict__ hbf, const __bf16* __restrict__ wf,
    float* __restrict__ xh, int M,
    const float* __restrict__ att_src, const float* __restrict__ att_dst,
    float* __restrict__ a_s, float* __restrict__ a_d,
    const float* __restrict__ bias, const float* __restrict__ gate_w2,
    const float* __restrict__ gate_b2, float* __restrict__ gate_out) {
    int tid = threadIdx.x;
    int w = tid >> 6, lane = tid & 63;
    int q = lane >> 4, r15 = lane & 15;
    int m0 = blockIdx.x * 64;
    int y = blockIdx.y;
    int arow = m0 + w * 16 + r15;
    int arowc = min(arow, M - 1);
    const __bf16* ap = hbf + (size_t)arowc * DD + q * 8;
    const bf16x8* bp0 = (const bf16x8*)wf + (size_t)(y * 8) * 4 * 64 + lane;
    f32x4 acc[4];
    #pragma unroll
    for (int t = 0; t < 4; ++t) acc[t] = (f32x4){0.f, 0.f, 0.f, 0.f};
    #pragma unroll
    for (int ks = 0; ks < 8; ++ks) {
        bf16x8 a = *(const bf16x8*)(ap + ks * 32);
        const bf16x8* bp = bp0 + (size_t)ks * 4 * 64;
        #pragma unroll
        for (int t = 0; t < 4; ++t) {
            bf16x8 b = bp[(size_t)t * 64];
            acc[t] = __builtin_amdgcn_mfma_f32_16x16x32_bf16(a, b, acc[t], 0, 0, 0);
        }
    }
    if (xh) {
        #pragma unroll
        for (int t = 0; t < 4; ++t) {
            int col = y * 64 + t * 16 + r15;
            #pragma unroll
            for (int r = 0; r < 4; ++r) {
                int rc = m0 + w * 16 + q * 4 + r;
                if (rc < M) xh[(size_t)rc * DD + col] = acc[t][r];
            }
        }
    }
    if (att_src) {
        #pragma unroll
        for (int r = 0; r < 4; ++r) {
            float ps = 0.f, pd = 0.f;
            #pragma unroll
            for (int t = 0; t < 4; ++t) {
                int col = y * 64 + t * 16 + r15;
                ps += acc[t][r] * att_src[col];
                pd += acc[t][r] * att_dst[col];
            }
            #pragma unroll
            for (int mask = 1; mask < 16; mask <<= 1) {
                ps += __shfl_xor(ps, mask, 64);
                pd += __shfl_xor(pd, mask, 64);
            }
            int rc = m0 + w * 16 + q * 4 + r;
            if (r15 == 0 && rc < M) {
                a_s[rc * HH + y] = ps;
                a_d[rc * HH + y] = pd;
            }
        }
    }
    if (gate_w2) {
        #pragma unroll
        for (int r = 0; r < 4; ++r) {
            float pg = 0.f;
            #pragma unroll
            for (int t = 0; t < 4; ++t) {
                int col = y * 64 + t * 16 + r15;
                pg += fmaxf(acc[t][r] + bias[col], 0.f) * gate_w2[col];
            }
            #pragma unroll
            for (int mask = 1; mask < 16; mask <<= 1) pg += __shfl_xor(pg, mask, 64);
            int rc = m0 + w * 16 + q * 4 + r;
            if (r15 == 0 && rc < M) {
                float add = pg + (y == 0 ? gate_b2[0] : 0.f);
                atomicAdd(&gate_out[rc], add);
            }
        }
    }
}

// ---------------------------------------------------------------------------
// K6 v4: WAVE-PER-NODE fused alpha + softmax + aggregation + LN + residual.
__global__ __launch_bounds__(256) void gat_message4_kernel(
    const float* __restrict__ xh, const float* __restrict__ a_s,
    const float* __restrict__ a_d, const float* __restrict__ a_e,  // + l*4; [e][20]
    const int* __restrict__ row_ptr, const int* __restrict__ csr_src,
    const int* __restrict__ csr_eid, const float* __restrict__ gat_b,
    const float* __restrict__ ln_g, const float* __restrict__ ln_b,
    float* __restrict__ h, __bf16* __restrict__ hbf, int N, int E) {
    __shared__ float lws[4][WCAP * 4];   // 12 KB: [wave][kk*4 + head]
    int tid = threadIdx.x;
    int w = tid >> 6, lane = tid & 63;
    int n = blockIdx.x * 4 + w;
    if (n >= N) return;
    int hh = lane >> 4, j = lane & 15;
    int rs = row_ptr[n], re = row_ptr[n + 1];
    int deg = re - rs;
    float adn = a_d[n * HH + hh];
    float al_self = lrelu(a_s[n * HH + hh] + adn + a_e[(size_t)(E + n) * LH + hh]);
    float m = al_self, den = 0.f;
    for (int k = rs + j; k < re; k += 16) {
        int kk = k - rs;
        int s = csr_src[k];
        int eid = csr_eid[k];
        float a = lrelu(a_s[s * HH + hh] + adn + a_e[(size_t)eid * LH + hh]);
        if (kk < WCAP) lws[w][kk * 4 + hh] = a;
        float mn = fmaxf(m, a);
        den = den * __expf(m - mn) + __expf(a - mn);
        m = mn;
    }
    #pragma unroll
    for (int off = 1; off < 16; off <<= 1) {
        float m2 = __shfl_xor(m, off, 64);
        float d2 = __shfl_xor(den, off, 64);
        float mn = fmaxf(m, m2);
        den = den * __expf(m - mn) + d2 * __expf(m2 - mn);
        m = mn;
    }
    den += __expf(al_self - m);
    float inv_den = 1.0f / den;
    int cap = min(deg, WCAP);
    for (int kk = j; kk < cap; kk += 16)
        lws[w][kk * 4 + hh] = __expf(lws[w][kk * 4 + hh] - m) * inv_den;
    float wself = __expf(al_self - m) * inv_den;
    const float4* xrow = (const float4*)(xh + (size_t)n * DD) + lane;
    float4 xs = *xrow;
    float4 acc;
    acc.x = wself * xs.x; acc.y = wself * xs.y;
    acc.z = wself * xs.z; acc.w = wself * xs.w;
    for (int k = rs; k < re; ++k) {
        int kk = k - rs;
        int s = csr_src[k];
        float wgt;
        if (kk < WCAP) wgt = lws[w][kk * 4 + hh];
        else {
            float a = lrelu(a_s[s * HH + hh] + adn + a_e[(size_t)csr_eid[k] * LH + hh]);
            wgt = __expf(a - m) * inv_den;
        }
        float4 xr = *((const float4*)(xh + (size_t)s * DD) + lane);
        acc.x += wgt * xr.x; acc.y += wgt * xr.y;
        acc.z += wgt * xr.z; acc.w += wgt * xr.w;
    }
    float4 gb = *((const float4*)gat_b + lane);
    float4 val;
    val.x = acc.x + gb.x; val.y = acc.y + gb.y;
    val.z = acc.z + gb.z; val.w = acc.w + gb.w;
    float s1 = val.x + val.y + val.z + val.w;
    float s2 = val.x * val.x + val.y * val.y + val.z * val.z + val.w * val.w;
    #pragma unroll
    for (int off = 1; off < 64; off <<= 1) {
        s1 += __shfl_xor(s1, off, 64);
        s2 += __shfl_xor(s2, off, 64);
    }
    float mu = s1 * (1.0f / DD);
    float var = s2 * (1.0f / DD) - mu * mu;
    float rstd = rsqrtf(var + 1e-5f);
    float4 lg = *((const float4*)ln_g + lane);
    float4 lb = *((const float4*)ln_b + lane);
    float4 nv;
    nv.x = fmaxf((val.x - mu) * rstd * lg.x + lb.x, 0.f);
    nv.y = fmaxf((val.y - mu) * rstd * lg.y + lb.y, 0.f);
    nv.z = fmaxf((val.z - mu) * rstd * lg.z + lb.z, 0.f);
    nv.w = fmaxf((val.w - mu) * rstd * lg.w + lb.w, 0.f);
    float4* hp = (float4*)(h + (size_t)n * DD) + lane;
    float4 hv = *hp;
    hv.x += nv.x; hv.y += nv.y; hv.z += nv.z; hv.w += nv.w;
    *hp = hv;
    bf16x4 hb;
    hb[0] = (__bf16)hv.x; hb[1] = (__bf16)hv.y;
    hb[2] = (__bf16)hv.z; hb[3] = (__bf16)hv.w;
    *((bf16x4*)(hbf + (size_t)n * DD) + lane) = hb;
}

// ---------------------------------------------------------------------------
__global__ void bstart_kernel(const int* __restrict__ batch, int* __restrict__ bstart,
                              int N, int B) {
    int b = threadIdx.x;
    if (b > B) return;
    int lo = 0, hi = N;
    while (lo < hi) {
        int mid = (lo + hi) >> 1;
        if (batch[mid] < b) lo = mid + 1; else hi = mid;
    }
    bstart[b] = lo;
}

__global__ __launch_bounds__(256) void gseg_kernel(
    const float* __restrict__ gate, const int* __restrict__ bstart,
    float* __restrict__ gmax, float* __restrict__ gden) {
    int b = blockIdx.x;
    int tid = threadIdx.x;
    int s0 = bstart[b], s1 = bstart[b + 1];
    __shared__ float red[256];
    float m = -1e30f;
    for (int i = s0 + tid; i < s1; i += 256) m = fmaxf(m, gate[i]);
    red[tid] = m;
    __syncthreads();
    for (int off = 128; off; off >>= 1) {
        if (tid < off) red[tid] = fmaxf(red[tid], red[tid + off]);
        __syncthreads();
    }
    float gm = red[0];
    __syncthreads();
    float s = 0.f;
    for (int i = s0 + tid; i < s1; i += 256) s += __expf(gate[i] - gm);
    red[tid] = s;
    __syncthreads();
    for (int off = 128; off; off >>= 1) {
        if (tid < off) red[tid] += red[tid + off];
        __syncthreads();
    }
    if (tid == 0) {
        gmax[b] = gm;
        gden[b] = red[0];
    }
}

__global__ void wgt_kernel(const float* __restrict__ gate, const int* __restrict__ batch,
                           const float* __restrict__ gmax, const float* __restrict__ gden,
                           float* __restrict__ wgt, int N) {
    int n = blockIdx.x * 256 + threadIdx.x;
    if (n >= N) return;
    int b = batch[n];
    wgt[n] = __expf(gate[n] - gmax[b]) / gden[b];
}

#define POOL_CHUNK 32
__global__ __launch_bounds__(256) void pool_scatter_kernel(
    const float* __restrict__ h, const float* __restrict__ wgt,
    const int* __restrict__ batch, float* __restrict__ g_embed, int N) {
    int i0 = blockIdx.x * POOL_CHUNK;
    int d = threadIdx.x;
    int iend = min(i0 + POOL_CHUNK, N);
    float acc = 0.f;
    int cur = batch[i0];
    for (int i = i0; i < iend; ++i) {
        int b = batch[i];
        if (b != cur) {
            atomicAdd(&g_embed[cur * DD + d], acc);
            acc = 0.f;
            cur = b;
        }
        acc += wgt[i] * h[(size_t)i * DD + d];
    }
    atomicAdd(&g_embed[cur * DD + d], acc);
}

__global__ __launch_bounds__(256) void readout_kernel(
    const float* __restrict__ g_embed, const float* __restrict__ w1,
    const float* __restrict__ b1, const float* __restrict__ w2,
    const float* __restrict__ b2, float* __restrict__ out) {
    int b = blockIdx.x;
    int tid = threadIdx.x;
    __shared__ float gvec[256];
    __shared__ float hid[256];
    gvec[tid] = g_embed[b * DD + tid];
    __syncthreads();
    float hv = b1[tid];
    for (int k = 0; k < DD; ++k) hv += gvec[k] * w1[k * DD + tid];
    hid[tid] = fmaxf(hv, 0.f);
    __syncthreads();
    float o = b2[tid];
    for (int t = 0; t < DD; ++t) o += hid[t] * w2[t * DD + tid];
    out[b * DD + tid] = o;
}

// ---------------------------------------------------------------------------
extern "C" void kernel_launch(void* const* d_in, const int* in_sizes, int n_in,
                              void* d_out, int out_size, void* d_ws, size_t ws_size,
                              hipStream_t stream) {
    const float* x        = (const float*)d_in[0];
    const float* edge_attr= (const float*)d_in[1];
    const int*   edge_idx = (const int*)d_in[2];
    const int*   batch    = (const int*)d_in[3];
    const float* enc_w    = (const float*)d_in[4];
    const float* enc_b    = (const float*)d_in[5];
    const float* eenc_w   = (const float*)d_in[6];
    const float* eenc_b   = (const float*)d_in[7];
    const float* gat_w    = (const float*)d_in[8];
    const float* att_src  = (const float*)d_in[9];
    const float* att_dst  = (const float*)d_in[10];
    const float* att_edge = (const float*)d_in[11];
    const float* gat_ew   = (const float*)d_in[12];
    const float* gat_b    = (const float*)d_in[13];
    const float* ln_g     = (const float*)d_in[14];
    const float* ln_b     = (const float*)d_in[15];
    const float* gate_w1  = (const float*)d_in[16];
    const float* gate_b1  = (const float*)d_in[17];
    const float* gate_w2  = (const float*)d_in[18];
    const float* gate_b2  = (const float*)d_in[19];
    const float* ro_w1    = (const float*)d_in[20];
    const float* ro_b1    = (const float*)d_in[21];
    const float* ro_w2    = (const float*)d_in[22];
    const float* ro_b2    = (const float*)d_in[23];
    float* out = (float*)d_out;

    const int N = in_sizes[0] / 42;       // 10000
    const int E = in_sizes[1] / 12;       // 160000
    const int B = out_size / DD;          // 16

    // workspace carve-up
    char* p = (char*)d_ws;
    auto alloc = [&](size_t bytes) {
        char* r = p;
        p += (bytes + 255) & ~(size_t)255;
        return (void*)r;
    };
    float*  h       = (float*)alloc((size_t)N * DD * 4);
    __bf16* hbf     = (__bf16*)alloc((size_t)N * DD * 2);
    float*  xh      = (float*)alloc((size_t)N * DD * 4);
    float*  a_s     = (float*)alloc((size_t)N * HH * 4);
    float*  a_d     = (float*)alloc((size_t)N * HH * 4);
    float*  a_e_all = (float*)alloc((size_t)(E + N) * LH * 4);  // [e][l*4+h]
    float*  wproj   = (float*)alloc((size_t)DD * LH * 4);
    __bf16* wfe     = (__bf16*)alloc((size_t)16 * 64 * 8 * 2);  // stage-A B-frags
    __bf16* wfp     = (__bf16*)alloc((size_t)16 * 64 * 8 * 2);  // stage-B B-frags
    __bf16* wf      = (__bf16*)alloc((size_t)6 * DD * DD * 2);  // swizzled bf16 weights
    float*  gate    = (float*)alloc((size_t)N * 4);
    float*  g_embed = (float*)alloc((size_t)B * DD * 4);
    float*  gmax    = (float*)alloc((size_t)B * 4);
    float*  gden    = (float*)alloc((size_t)B * 4);
    float*  wgt     = (float*)alloc((size_t)N * 4);
    int* deg        = (int*)alloc((size_t)N * 4);
    int* row_ptr    = (int*)alloc((size_t)(N + 1) * 4);
    int* cursor     = (int*)alloc((size_t)N * 4);
    int* csr_src    = (int*)alloc((size_t)E * 4);
    int* csr_eid    = (int*)alloc((size_t)E * 4);
    int* bstart     = (int*)alloc((size_t)(B + 1) * 4);

    const int* src_arr = edge_idx;
    const int* dst_arr = edge_idx + E;

    hipMemsetAsync(deg, 0, (size_t)N * 4, stream);
    hipMemsetAsync(g_embed, 0, (size_t)B * DD * 4, stream);
    hipMemsetAsync(gate, 0, (size_t)N * 4, stream);

    wproj_kernel<<<LL, 256, 0, stream>>>(gat_ew, att_edge, wproj);
    pack_edge_frags_kernel<<<1, 256, 0, stream>>>(eenc_w, eenc_b, wproj, wfe, wfp);
    wswizzle_kernel<<<192, 256, 0, stream>>>(gat_w, gate_w1, wf);
    encoder_kernel<<<N, 256, 0, stream>>>(x, enc_w, enc_b, h, hbf, N);
    deg_kernel<<<(E + 255) / 256, 256, 0, stream>>>(dst_arr, deg, E);
    scan_kernel<<<1, 1024, 0, stream>>>(deg, row_ptr, N);
    copy_int_kernel<<<(N + 255) / 256, 256, 0, stream>>>(row_ptr, cursor, N);
    scatter_kernel<<<(E + 255) / 256, 256, 0, stream>>>(
        src_arr, dst_arr, cursor, csr_src, csr_eid, E);
    edge_mfma_kernel<<<(E + 63) / 64, 256, 0, stream>>>(
        edge_attr, wfe, wfp, a_e_all, E);
    self_ae_kernel<<<(N * LH + 255) / 256, 256, 0, stream>>>(
        row_ptr, csr_eid, a_e_all, N, E);

    dim3 ggrid((N + 63) / 64, 4);
    for (int l = 0; l < LL; ++l) {
        gemm_mfma_kernel<<<ggrid, 256, 0, stream>>>(
            hbf, wf + (size_t)l * DD * DD, xh, N,
            att_src + l * DD, att_dst + l * DD, a_s, a_d,
            nullptr, nullptr, nullptr, nullptr);
        gat_message4_kernel<<<(N + 3) / 4, 256, 0, stream>>>(
            xh, a_s, a_d, a_e_all + l * HH, row_ptr, csr_src, csr_eid,
            gat_b + l * DD, ln_g + l * DD, ln_b + l * DD, h, hbf, N, E);
    }

    // pooling gate: gate[n] = relu(h@gate_w1+b1) . gate_w2 + b2, fused MFMA
    gemm_mfma_kernel<<<ggrid, 256, 0, stream>>>(
        hbf, wf + (size_t)5 * DD * DD, nullptr, N,
        nullptr, nullptr, nullptr, nullptr,
        gate_b1, gate_w2, gate_b2, gate);
    bstart_kernel<<<1, 32, 0, stream>>>(batch, bstart, N, B);
    gseg_kernel<<<B, 256, 0, stream>>>(gate, bstart, gmax, gden);
    wgt_kernel<<<(N + 255) / 256, 256, 0, stream>>>(gate, batch, gmax, gden, wgt, N);
    pool_scatter_kernel<<<(N + POOL_CHUNK - 1) / POOL_CHUNK, 256, 0, stream>>>(
        h, wgt, batch, g_embed, N);
    readout_kernel<<<B, 256, 0, stream>>>(g_embed, ro_w1, ro_b1, ro_w2, ro_b2, out);
}

// Round 13
// 465.998 us; speedup vs baseline: 1.4207x; 1.0617x over previous
//
#include <hip/hip_runtime.h>
#include <math.h>

// Problem constants (fixed-shape problem)
#define DD 256
#define HH 4
#define CC 64
#define LL 5
#define NEG_SLOPE 0.2f
#define LH 20   // L*H
#define WCAP 192  // per-wave LDS softmax-weight cache

typedef __bf16 bf16x8 __attribute__((ext_vector_type(8)));
typedef __bf16 bf16x4 __attribute__((ext_vector_type(4)));
typedef float f32x4 __attribute__((ext_vector_type(4)));

static __device__ __forceinline__ float lrelu(float x) {
    return x > 0.0f ? x : NEG_SLOPE * x;
}

// ---------------------------------------------------------------------------
// K0: wproj[k][l*4+h] = sum_c gat_ew[l][k][h*64+c] * att_edge[l][h][c]
__global__ __launch_bounds__(256) void wproj_kernel(
    const float* __restrict__ gat_ew, const float* __restrict__ att_edge,
    float* __restrict__ wproj) {
    int l = blockIdx.x;
    int k = threadIdx.x;
    const float* W = gat_ew + (size_t)l * DD * DD;
    const float* att = att_edge + l * DD;  // [H][C] flat = 256
    for (int hh = 0; hh < HH; ++hh) {
        float s = 0.f;
        #pragma unroll
        for (int c = 0; c < CC; ++c)
            s += W[k * DD + hh * CC + c] * att[hh * CC + c];
        wproj[k * LH + l * HH + hh] = s;
    }
}

// K0b: pack edge-encoder + wproj weights into MFMA B-fragment order (bf16).
__global__ __launch_bounds__(256) void pack_edge_frags_kernel(
    const float* __restrict__ eenc_w, const float* __restrict__ eenc_b,
    const float* __restrict__ wproj, __bf16* __restrict__ wfe,
    __bf16* __restrict__ wfp) {
    int tid = threadIdx.x;
    for (int idx = tid; idx < 16 * 64; idx += 256) {
        int t = idx >> 6, lane = idx & 63;
        int q = lane >> 4, r15 = lane & 15;
        int col = t * 16 + r15;
        #pragma unroll
        for (int j = 0; j < 8; ++j) {
            int k = q * 8 + j;
            float v = (k < 12) ? eenc_w[k * 256 + col]
                               : (k == 12 ? eenc_b[col] : 0.f);
            wfe[(size_t)idx * 8 + j] = (__bf16)v;
        }
    }
    for (int idx = tid; idx < 16 * 64; idx += 256) {
        int sidx = idx >> 6, lane = idx & 63;
        int s = sidx >> 1, t2 = sidx & 1;
        int q = lane >> 4, r15 = lane & 15;
        int col = t2 * 16 + r15;
        #pragma unroll
        for (int j = 0; j < 8; ++j) {
            int k = s * 32 + q * 8 + j;
            float v = (col < LH) ? wproj[k * LH + col] : 0.f;
            wfp[(size_t)idx * 8 + j] = (__bf16)v;
        }
    }
}

// ---------------------------------------------------------------------------
// K0c: swizzle GEMM weights into MFMA B-fragment order, bf16.
// l in 0..4 = gat_w layers; l = 5 = gate_w1.
__global__ __launch_bounds__(256) void wswizzle_kernel(
    const float* __restrict__ gat_w, const float* __restrict__ gate_w1,
    __bf16* __restrict__ wf) {
    int b = blockIdx.x;           // l*32 + y*8 + ks
    int l = b >> 5;
    int rem = b & 31;
    int y = rem >> 3, ks = rem & 7;
    int tid = threadIdx.x;
    int t = tid >> 6, lane = tid & 63;
    int q = lane >> 4, r15 = lane & 15;
    const float* W = (l < 5) ? (gat_w + (size_t)l * DD * DD) : gate_w1;
    size_t obase = (((size_t)b * 4 + t) * 64 + lane) * 8;
    int kbase = ks * 32 + q * 8;
    int col = y * 64 + t * 16 + r15;
    #pragma unroll
    for (int j = 0; j < 8; ++j)
        wf[obase + j] = (__bf16)W[(size_t)(kbase + j) * DD + col];
}

// ---------------------------------------------------------------------------
// K1: node encoder h = relu(x @ enc_w + enc_b); also writes bf16 shadow
__global__ __launch_bounds__(256) void encoder_kernel(
    const float* __restrict__ x, const float* __restrict__ enc_w,
    const float* __restrict__ enc_b, float* __restrict__ h,
    __bf16* __restrict__ hbf, int N) {
    int n = blockIdx.x;
    int tid = threadIdx.x;
    __shared__ float xs[42];
    if (tid < 42) xs[tid] = x[(size_t)n * 42 + tid];
    __syncthreads();
    float acc = enc_b[tid];
    #pragma unroll
    for (int f = 0; f < 42; ++f) acc += xs[f] * enc_w[f * DD + tid];
    float v = fmaxf(acc, 0.f);
    h[(size_t)n * DD + tid] = v;
    hbf[(size_t)n * DD + tid] = (__bf16)v;
}

// ---------------------------------------------------------------------------
// K2 v5: edge_pre on matrix cores (16 edges/wave, two MFMA stages).
__global__ __launch_bounds__(256) void edge_mfma_kernel(
    const float* __restrict__ edge_attr, const __bf16* __restrict__ wfe,
    const __bf16* __restrict__ wfp, float* __restrict__ a_e_all, int E) {
    __shared__ __bf16 sm[4][16][264];   // 33 KB
    int tid = threadIdx.x;
    int w = tid >> 6, lane = tid & 63;
    int q = lane >> 4, r15 = lane & 15;
    int eb = blockIdx.x * 64 + w * 16;
    int e = eb + r15;
    int ec = min(e, E - 1);
    bf16x8 a1;
    #pragma unroll
    for (int j = 0; j < 8; ++j) a1[j] = (__bf16)0.f;
    if (q == 0) {
        const float4* p = (const float4*)(edge_attr + (size_t)ec * 12);
        float4 p0 = p[0], p1 = p[1];
        a1[0] = (__bf16)p0.x; a1[1] = (__bf16)p0.y; a1[2] = (__bf16)p0.z; a1[3] = (__bf16)p0.w;
        a1[4] = (__bf16)p1.x; a1[5] = (__bf16)p1.y; a1[6] = (__bf16)p1.z; a1[7] = (__bf16)p1.w;
    } else if (q == 1) {
        float4 p2 = *(const float4*)(edge_attr + (size_t)ec * 12 + 8);
        a1[0] = (__bf16)p2.x; a1[1] = (__bf16)p2.y; a1[2] = (__bf16)p2.z; a1[3] = (__bf16)p2.w;
        a1[4] = (__bf16)1.0f;  // k = 12: bias row
    }
    const bf16x8* wfeP = (const bf16x8*)wfe;
    f32x4 zero = (f32x4){0.f, 0.f, 0.f, 0.f};
    #pragma unroll
    for (int t = 0; t < 16; ++t) {
        bf16x8 bfr = wfeP[t * 64 + lane];
        f32x4 c = __builtin_amdgcn_mfma_f32_16x16x32_bf16(a1, bfr, zero, 0, 0, 0);
        int col = t * 16 + r15;
        #pragma unroll
        for (int r = 0; r < 4; ++r)
            sm[w][q * 4 + r][col] = (__bf16)fmaxf(c[r], 0.f);
    }
    const bf16x8* wfpP = (const bf16x8*)wfp;
    f32x4 c2[2];
    c2[0] = zero; c2[1] = zero;
    #pragma unroll
    for (int s = 0; s < 8; ++s) {
        bf16x8 a2 = *(const bf16x8*)&sm[w][r15][s * 32 + q * 8];
        #pragma unroll
        for (int t2 = 0; t2 < 2; ++t2)
            c2[t2] = __builtin_amdgcn_mfma_f32_16x16x32_bf16(
                a2, wfpP[(s * 2 + t2) * 64 + lane], c2[t2], 0, 0, 0);
    }
    #pragma unroll
    for (int t2 = 0; t2 < 2; ++t2) {
        int col = t2 * 16 + r15;
        if (col >= LH) continue;
        #pragma unroll
        for (int r = 0; r < 4; ++r) {
            int e2 = eb + q * 4 + r;
            if (e2 < E) a_e_all[(size_t)e2 * LH + col] = c2[t2][r];
        }
    }
}

// ---------------------------------------------------------------------------
__global__ void deg_kernel(const int* __restrict__ dst, int* __restrict__ deg, int E) {
    int e = blockIdx.x * 256 + threadIdx.x;
    if (e < E) atomicAdd(&deg[dst[e]], 1);
}

__global__ void self_ae_kernel(const int* __restrict__ row_ptr,
                               const int* __restrict__ csr_eid,
                               float* __restrict__ a_e_all, int N, int E) {
    int i = blockIdx.x * 256 + threadIdx.x;
    if (i >= N * LH) return;
    int n = i / LH;
    int j = i % LH;
    int rs = row_ptr[n], re = row_ptr[n + 1];
    float s = 0.f;
    for (int k = rs; k < re; ++k)
        s += a_e_all[(size_t)csr_eid[k] * LH + j];
    a_e_all[(size_t)(E + n) * LH + j] = s / (float)max(re - rs, 1);
}

// K4: exclusive prefix scan of deg -> row_ptr AND cursor (single block)
__global__ __launch_bounds__(1024) void scan_kernel(const int* __restrict__ deg,
                                                    int* __restrict__ row_ptr,
                                                    int* __restrict__ cursor, int n) {
    __shared__ int buf[1024];
    __shared__ int carry_s;
    int tid = threadIdx.x;
    if (tid == 0) carry_s = 0;
    __syncthreads();
    for (int base = 0; base < n; base += 1024) {
        int i = base + tid;
        int v = (i < n) ? deg[i] : 0;
        buf[tid] = v;
        __syncthreads();
        for (int off = 1; off < 1024; off <<= 1) {
            int t = (tid >= off) ? buf[tid - off] : 0;
            __syncthreads();
            buf[tid] += t;
            __syncthreads();
        }
        int carry = carry_s;
        if (i < n) {
            int ex = carry + buf[tid] - v;
            row_ptr[i] = ex;
            cursor[i] = ex;
        }
        __syncthreads();
        if (tid == 1023) carry_s = carry + buf[1023];
        __syncthreads();
    }
    if (tid == 0) row_ptr[n] = carry_s;
}

__global__ void scatter_kernel(const int* __restrict__ src, const int* __restrict__ dst,
                               int* __restrict__ cursor, int* __restrict__ csr_src,
                               int* __restrict__ csr_eid, int E) {
    int e = blockIdx.x * 256 + threadIdx.x;
    if (e >= E) return;
    int d = dst[e];
    int pos = atomicAdd(&cursor[d], 1);
    csr_src[pos] = src[e];
    csr_eid[pos] = e;
}

// ---------------------------------------------------------------------------
// MFMA GEMM: xhbf[M,256] (bf16) = hbf @ W. 64x64 tile/block, blockIdx.y = head.
// No LDS/barriers. Fused epilogues (a_s/a_d or gate).
__global__ __launch_bounds__(256) void gemm_mfma_kernel(
    const __bf16* __restrict__ hbf, const __bf16* __restrict__ wf,
    __bf16* __restrict__ xhbf, int M,
    const float* __restrict__ att_src, const float* __restrict__ att_dst,
    float* __restrict__ a_s, float* __restrict__ a_d,
    const float* __restrict__ bias, const float* __restrict__ gate_w2,
    const float* __restrict__ gate_b2, float* __restrict__ gate_out) {
    int tid = threadIdx.x;
    int w = tid >> 6, lane = tid & 63;
    int q = lane >> 4, r15 = lane & 15;
    int m0 = blockIdx.x * 64;
    int y = blockIdx.y;
    int arow = m0 + w * 16 + r15;
    int arowc = min(arow, M - 1);
    const __bf16* ap = hbf + (size_t)arowc * DD + q * 8;
    const bf16x8* bp0 = (const bf16x8*)wf + (size_t)(y * 8) * 4 * 64 + lane;
    f32x4 acc[4];
    #pragma unroll
    for (int t = 0; t < 4; ++t) acc[t] = (f32x4){0.f, 0.f, 0.f, 0.f};
    #pragma unroll
    for (int ks = 0; ks < 8; ++ks) {
        bf16x8 a = *(const bf16x8*)(ap + ks * 32);
        const bf16x8* bp = bp0 + (size_t)ks * 4 * 64;
        #pragma unroll
        for (int t = 0; t < 4; ++t) {
            bf16x8 b = bp[(size_t)t * 64];
            acc[t] = __builtin_amdgcn_mfma_f32_16x16x32_bf16(a, b, acc[t], 0, 0, 0);
        }
    }
    if (xhbf) {
        #pragma unroll
        for (int t = 0; t < 4; ++t) {
            int col = y * 64 + t * 16 + r15;
            #pragma unroll
            for (int r = 0; r < 4; ++r) {
                int rc = m0 + w * 16 + q * 4 + r;
                if (rc < M) xhbf[(size_t)rc * DD + col] = (__bf16)acc[t][r];
            }
        }
    }
    if (att_src) {
        #pragma unroll
        for (int r = 0; r < 4; ++r) {
            float ps = 0.f, pd = 0.f;
            #pragma unroll
            for (int t = 0; t < 4; ++t) {
                int col = y * 64 + t * 16 + r15;
                ps += acc[t][r] * att_src[col];
                pd += acc[t][r] * att_dst[col];
            }
            #pragma unroll
            for (int mask = 1; mask < 16; mask <<= 1) {
                ps += __shfl_xor(ps, mask, 64);
                pd += __shfl_xor(pd, mask, 64);
            }
            int rc = m0 + w * 16 + q * 4 + r;
            if (r15 == 0 && rc < M) {
                a_s[rc * HH + y] = ps;
                a_d[rc * HH + y] = pd;
            }
        }
    }
    if (gate_w2) {
        #pragma unroll
        for (int r = 0; r < 4; ++r) {
            float pg = 0.f;
            #pragma unroll
            for (int t = 0; t < 4; ++t) {
                int col = y * 64 + t * 16 + r15;
                pg += fmaxf(acc[t][r] + bias[col], 0.f) * gate_w2[col];
            }
            #pragma unroll
            for (int mask = 1; mask < 16; mask <<= 1) pg += __shfl_xor(pg, mask, 64);
            int rc = m0 + w * 16 + q * 4 + r;
            if (r15 == 0 && rc < M) {
                float add = pg + (y == 0 ? gate_b2[0] : 0.f);
                atomicAdd(&gate_out[rc], add);
            }
        }
    }
}

// ---------------------------------------------------------------------------
// K6 v5: WAVE-PER-NODE, bf16 xh gather (half traffic), fp32 accumulate.
__global__ __launch_bounds__(256) void gat_message5_kernel(
    const __bf16* __restrict__ xhbf, const float* __restrict__ a_s,
    const float* __restrict__ a_d, const float* __restrict__ a_e,  // + l*4; [e][20]
    const int* __restrict__ row_ptr, const int* __restrict__ csr_src,
    const int* __restrict__ csr_eid, const float* __restrict__ gat_b,
    const float* __restrict__ ln_g, const float* __restrict__ ln_b,
    float* __restrict__ h, __bf16* __restrict__ hbf, int N, int E) {
    __shared__ float lws[4][WCAP * 4];   // 12 KB: [wave][kk*4 + head]
    int tid = threadIdx.x;
    int w = tid >> 6, lane = tid & 63;
    int n = blockIdx.x * 4 + w;
    if (n >= N) return;
    int hh = lane >> 4, j = lane & 15;
    int rs = row_ptr[n], re = row_ptr[n + 1];
    int deg = re - rs;
    float adn = a_d[n * HH + hh];
    float al_self = lrelu(a_s[n * HH + hh] + adn + a_e[(size_t)(E + n) * LH + hh]);
    float m = al_self, den = 0.f;
    for (int k = rs + j; k < re; k += 16) {
        int kk = k - rs;
        int s = csr_src[k];
        int eid = csr_eid[k];
        float a = lrelu(a_s[s * HH + hh] + adn + a_e[(size_t)eid * LH + hh]);
        if (kk < WCAP) lws[w][kk * 4 + hh] = a;
        float mn = fmaxf(m, a);
        den = den * __expf(m - mn) + __expf(a - mn);
        m = mn;
    }
    #pragma unroll
    for (int off = 1; off < 16; off <<= 1) {
        float m2 = __shfl_xor(m, off, 64);
        float d2 = __shfl_xor(den, off, 64);
        float mn = fmaxf(m, m2);
        den = den * __expf(m - mn) + d2 * __expf(m2 - mn);
        m = mn;
    }
    den += __expf(al_self - m);
    float inv_den = 1.0f / den;
    int cap = min(deg, WCAP);
    for (int kk = j; kk < cap; kk += 16)
        lws[w][kk * 4 + hh] = __expf(lws[w][kk * 4 + hh] - m) * inv_den;
    float wself = __expf(al_self - m) * inv_den;
    bf16x4 xsb = *((const bf16x4*)(xhbf + (size_t)n * DD) + lane);
    float4 acc;
    acc.x = wself * (float)xsb[0]; acc.y = wself * (float)xsb[1];
    acc.z = wself * (float)xsb[2]; acc.w = wself * (float)xsb[3];
    for (int k = rs; k < re; ++k) {
        int kk = k - rs;
        int s = csr_src[k];
        float wgt;
        if (kk < WCAP) wgt = lws[w][kk * 4 + hh];
        else {
            float a = lrelu(a_s[s * HH + hh] + adn + a_e[(size_t)csr_eid[k] * LH + hh]);
            wgt = __expf(a - m) * inv_den;
        }
        bf16x4 xrb = *((const bf16x4*)(xhbf + (size_t)s * DD) + lane);
        acc.x += wgt * (float)xrb[0]; acc.y += wgt * (float)xrb[1];
        acc.z += wgt * (float)xrb[2]; acc.w += wgt * (float)xrb[3];
    }
    float4 gb = *((const float4*)gat_b + lane);
    float4 val;
    val.x = acc.x + gb.x; val.y = acc.y + gb.y;
    val.z = acc.z + gb.z; val.w = acc.w + gb.w;
    float s1 = val.x + val.y + val.z + val.w;
    float s2 = val.x * val.x + val.y * val.y + val.z * val.z + val.w * val.w;
    #pragma unroll
    for (int off = 1; off < 64; off <<= 1) {
        s1 += __shfl_xor(s1, off, 64);
        s2 += __shfl_xor(s2, off, 64);
    }
    float mu = s1 * (1.0f / DD);
    float var = s2 * (1.0f / DD) - mu * mu;
    float rstd = rsqrtf(var + 1e-5f);
    float4 lg = *((const float4*)ln_g + lane);
    float4 lb = *((const float4*)ln_b + lane);
    float4 nv;
    nv.x = fmaxf((val.x - mu) * rstd * lg.x + lb.x, 0.f);
    nv.y = fmaxf((val.y - mu) * rstd * lg.y + lb.y, 0.f);
    nv.z = fmaxf((val.z - mu) * rstd * lg.z + lb.z, 0.f);
    nv.w = fmaxf((val.w - mu) * rstd * lg.w + lb.w, 0.f);
    float4* hp = (float4*)(h + (size_t)n * DD) + lane;
    float4 hv = *hp;
    hv.x += nv.x; hv.y += nv.y; hv.z += nv.z; hv.w += nv.w;
    *hp = hv;
    bf16x4 hb;
    hb[0] = (__bf16)hv.x; hb[1] = (__bf16)hv.y;
    hb[2] = (__bf16)hv.z; hb[3] = (__bf16)hv.w;
    *((bf16x4*)(hbf + (size_t)n * DD) + lane) = hb;
}

// ---------------------------------------------------------------------------
__global__ void bstart_kernel(const int* __restrict__ batch, int* __restrict__ bstart,
                              int N, int B) {
    int b = threadIdx.x;
    if (b > B) return;
    int lo = 0, hi = N;
    while (lo < hi) {
        int mid = (lo + hi) >> 1;
        if (batch[mid] < b) lo = mid + 1; else hi = mid;
    }
    bstart[b] = lo;
}

__global__ __launch_bounds__(256) void gseg_kernel(
    const float* __restrict__ gate, const int* __restrict__ bstart,
    float* __restrict__ gmax, float* __restrict__ gden) {
    int b = blockIdx.x;
    int tid = threadIdx.x;
    int s0 = bstart[b], s1 = bstart[b + 1];
    __shared__ float red[256];
    float m = -1e30f;
    for (int i = s0 + tid; i < s1; i += 256) m = fmaxf(m, gate[i]);
    red[tid] = m;
    __syncthreads();
    for (int off = 128; off; off >>= 1) {
        if (tid < off) red[tid] = fmaxf(red[tid], red[tid + off]);
        __syncthreads();
    }
    float gm = red[0];
    __syncthreads();
    float s = 0.f;
    for (int i = s0 + tid; i < s1; i += 256) s += __expf(gate[i] - gm);
    red[tid] = s;
    __syncthreads();
    for (int off = 128; off; off >>= 1) {
        if (tid < off) red[tid] += red[tid + off];
        __syncthreads();
    }
    if (tid == 0) {
        gmax[b] = gm;
        gden[b] = red[0];
    }
}

// K7d: pooled embedding; softmax weight computed inline (wgt_kernel fused).
#define POOL_CHUNK 32
__global__ __launch_bounds__(256) void pool_scatter_kernel(
    const float* __restrict__ h, const float* __restrict__ gate,
    const float* __restrict__ gmax, const float* __restrict__ gden,
    const int* __restrict__ batch, float* __restrict__ g_embed, int N) {
    int i0 = blockIdx.x * POOL_CHUNK;
    int d = threadIdx.x;
    int iend = min(i0 + POOL_CHUNK, N);
    float acc = 0.f;
    int cur = batch[i0];
    for (int i = i0; i < iend; ++i) {
        int b = batch[i];
        if (b != cur) {
            atomicAdd(&g_embed[cur * DD + d], acc);
            acc = 0.f;
            cur = b;
        }
        float wgt = __expf(gate[i] - gmax[b]) / gden[b];
        acc += wgt * h[(size_t)i * DD + d];
    }
    atomicAdd(&g_embed[cur * DD + d], acc);
}

__global__ __launch_bounds__(256) void readout_kernel(
    const float* __restrict__ g_embed, const float* __restrict__ w1,
    const float* __restrict__ b1, const float* __restrict__ w2,
    const float* __restrict__ b2, float* __restrict__ out) {
    int b = blockIdx.x;
    int tid = threadIdx.x;
    __shared__ float gvec[256];
    __shared__ float hid[256];
    gvec[tid] = g_embed[b * DD + tid];
    __syncthreads();
    float hv = b1[tid];
    for (int k = 0; k < DD; ++k) hv += gvec[k] * w1[k * DD + tid];
    hid[tid] = fmaxf(hv, 0.f);
    __syncthreads();
    float o = b2[tid];
    for (int t = 0; t < DD; ++t) o += hid[t] * w2[t * DD + tid];
    out[b * DD + tid] = o;
}

// ---------------------------------------------------------------------------
extern "C" void kernel_launch(void* const* d_in, const int* in_sizes, int n_in,
                              void* d_out, int out_size, void* d_ws, size_t ws_size,
                              hipStream_t stream) {
    const float* x        = (const float*)d_in[0];
    const float* edge_attr= (const float*)d_in[1];
    const int*   edge_idx = (const int*)d_in[2];
    const int*   batch    = (const int*)d_in[3];
    const float* enc_w    = (const float*)d_in[4];
    const float* enc_b    = (const float*)d_in[5];
    const float* eenc_w   = (const float*)d_in[6];
    const float* eenc_b   = (const float*)d_in[7];
    const float* gat_w    = (const float*)d_in[8];
    const float* att_src  = (const float*)d_in[9];
    const float* att_dst  = (const float*)d_in[10];
    const float* att_edge = (const float*)d_in[11];
    const float* gat_ew   = (const float*)d_in[12];
    const float* gat_b    = (const float*)d_in[13];
    const float* ln_g     = (const float*)d_in[14];
    const float* ln_b     = (const float*)d_in[15];
    const float* gate_w1  = (const float*)d_in[16];
    const float* gate_b1  = (const float*)d_in[17];
    const float* gate_w2  = (const float*)d_in[18];
    const float* gate_b2  = (const float*)d_in[19];
    const float* ro_w1    = (const float*)d_in[20];
    const float* ro_b1    = (const float*)d_in[21];
    const float* ro_w2    = (const float*)d_in[22];
    const float* ro_b2    = (const float*)d_in[23];
    float* out = (float*)d_out;

    const int N = in_sizes[0] / 42;       // 10000
    const int E = in_sizes[1] / 12;       // 160000
    const int B = out_size / DD;          // 16

    // workspace carve-up
    char* p = (char*)d_ws;
    auto alloc = [&](size_t bytes) {
        char* r = p;
        p += (bytes + 255) & ~(size_t)255;
        return (void*)r;
    };
    float*  h       = (float*)alloc((size_t)N * DD * 4);
    __bf16* hbf     = (__bf16*)alloc((size_t)N * DD * 2);
    __bf16* xhbf    = (__bf16*)alloc((size_t)N * DD * 2);
    float*  a_s     = (float*)alloc((size_t)N * HH * 4);
    float*  a_d     = (float*)alloc((size_t)N * HH * 4);
    float*  a_e_all = (float*)alloc((size_t)(E + N) * LH * 4);  // [e][l*4+h]
    float*  wproj   = (float*)alloc((size_t)DD * LH * 4);
    __bf16* wfe     = (__bf16*)alloc((size_t)16 * 64 * 8 * 2);  // stage-A B-frags
    __bf16* wfp     = (__bf16*)alloc((size_t)16 * 64 * 8 * 2);  // stage-B B-frags
    __bf16* wf      = (__bf16*)alloc((size_t)6 * DD * DD * 2);  // swizzled bf16 weights
    float*  gate    = (float*)alloc((size_t)N * 4);
    float*  g_embed = (float*)alloc((size_t)B * DD * 4);
    float*  gmax    = (float*)alloc((size_t)B * 4);
    float*  gden    = (float*)alloc((size_t)B * 4);
    int* deg        = (int*)alloc((size_t)N * 4);
    int* row_ptr    = (int*)alloc((size_t)(N + 1) * 4);
    int* cursor     = (int*)alloc((size_t)N * 4);
    int* csr_src    = (int*)alloc((size_t)E * 4);
    int* csr_eid    = (int*)alloc((size_t)E * 4);
    int* bstart     = (int*)alloc((size_t)(B + 1) * 4);

    const int* src_arr = edge_idx;
    const int* dst_arr = edge_idx + E;

    hipMemsetAsync(deg, 0, (size_t)N * 4, stream);
    hipMemsetAsync(g_embed, 0, (size_t)B * DD * 4, stream);
    hipMemsetAsync(gate, 0, (size_t)N * 4, stream);

    wproj_kernel<<<LL, 256, 0, stream>>>(gat_ew, att_edge, wproj);
    pack_edge_frags_kernel<<<1, 256, 0, stream>>>(eenc_w, eenc_b, wproj, wfe, wfp);
    wswizzle_kernel<<<192, 256, 0, stream>>>(gat_w, gate_w1, wf);
    encoder_kernel<<<N, 256, 0, stream>>>(x, enc_w, enc_b, h, hbf, N);
    deg_kernel<<<(E + 255) / 256, 256, 0, stream>>>(dst_arr, deg, E);
    scan_kernel<<<1, 1024, 0, stream>>>(deg, row_ptr, cursor, N);
    scatter_kernel<<<(E + 255) / 256, 256, 0, stream>>>(
        src_arr, dst_arr, cursor, csr_src, csr_eid, E);
    edge_mfma_kernel<<<(E + 63) / 64, 256, 0, stream>>>(
        edge_attr, wfe, wfp, a_e_all, E);
    self_ae_kernel<<<(N * LH + 255) / 256, 256, 0, stream>>>(
        row_ptr, csr_eid, a_e_all, N, E);

    dim3 ggrid((N + 63) / 64, 4);
    for (int l = 0; l < LL; ++l) {
        gemm_mfma_kernel<<<ggrid, 256, 0, stream>>>(
            hbf, wf + (size_t)l * DD * DD, xhbf, N,
            att_src + l * DD, att_dst + l * DD, a_s, a_d,
            nullptr, nullptr, nullptr, nullptr);
        gat_message5_kernel<<<(N + 3) / 4, 256, 0, stream>>>(
            xhbf, a_s, a_d, a_e_all + l * HH, row_ptr, csr_src, csr_eid,
            gat_b + l * DD, ln_g + l * DD, ln_b + l * DD, h, hbf, N, E);
    }

    // pooling gate: gate[n] = relu(h@gate_w1+b1) . gate_w2 + b2, fused MFMA
    gemm_mfma_kernel<<<ggrid, 256, 0, stream>>>(
        hbf, wf + (size_t)5 * DD * DD, nullptr, N,
        nullptr, nullptr, nullptr, nullptr,
        gate_b1, gate_w2, gate_b2, gate);
    bstart_kernel<<<1, 32, 0, stream>>>(batch, bstart, N, B);
    gseg_kernel<<<B, 256, 0, stream>>>(gate, bstart, gmax, gden);
    pool_scatter_kernel<<<(N + POOL_CHUNK - 1) / POOL_CHUNK, 256, 0, stream>>>(
        h, gate, gmax, gden, batch, g_embed, N);
    readout_kernel<<<B, 256, 0, stream>>>(g_embed, ro_w1, ro_b1, ro_w2, ro_b2, out);
}

// Round 14
// 438.295 us; speedup vs baseline: 1.5105x; 1.0632x over previous
//
#include <hip/hip_runtime.h>
#include <math.h>

// Problem constants (fixed-shape problem)
#define DD 256
#define HH 4
#define CC 64
#define LL 5
#define NEG_SLOPE 0.2f
#define LH 20   // L*H
#define WCAP 192  // per-wave LDS softmax-weight cache

typedef __bf16 bf16x8 __attribute__((ext_vector_type(8)));
typedef __bf16 bf16x4 __attribute__((ext_vector_type(4)));
typedef float f32x4 __attribute__((ext_vector_type(4)));

static __device__ __forceinline__ float lrelu(float x) {
    return x > 0.0f ? x : NEG_SLOPE * x;
}

// ---------------------------------------------------------------------------
// K0: wproj[k][l*4+h] = sum_c gat_ew[l][k][h*64+c] * att_edge[l][h][c]
__global__ __launch_bounds__(256) void wproj_kernel(
    const float* __restrict__ gat_ew, const float* __restrict__ att_edge,
    float* __restrict__ wproj) {
    int l = blockIdx.x;
    int k = threadIdx.x;
    const float* W = gat_ew + (size_t)l * DD * DD;
    const float* att = att_edge + l * DD;  // [H][C] flat = 256
    for (int hh = 0; hh < HH; ++hh) {
        float s = 0.f;
        #pragma unroll
        for (int c = 0; c < CC; ++c)
            s += W[k * DD + hh * CC + c] * att[hh * CC + c];
        wproj[k * LH + l * HH + hh] = s;
    }
}

// K0b: pack edge-encoder + wproj weights into MFMA B-fragment order (bf16).
__global__ __launch_bounds__(256) void pack_edge_frags_kernel(
    const float* __restrict__ eenc_w, const float* __restrict__ eenc_b,
    const float* __restrict__ wproj, __bf16* __restrict__ wfe,
    __bf16* __restrict__ wfp) {
    int tid = threadIdx.x;
    for (int idx = tid; idx < 16 * 64; idx += 256) {
        int t = idx >> 6, lane = idx & 63;
        int q = lane >> 4, r15 = lane & 15;
        int col = t * 16 + r15;
        #pragma unroll
        for (int j = 0; j < 8; ++j) {
            int k = q * 8 + j;
            float v = (k < 12) ? eenc_w[k * 256 + col]
                               : (k == 12 ? eenc_b[col] : 0.f);
            wfe[(size_t)idx * 8 + j] = (__bf16)v;
        }
    }
    for (int idx = tid; idx < 16 * 64; idx += 256) {
        int sidx = idx >> 6, lane = idx & 63;
        int s = sidx >> 1, t2 = sidx & 1;
        int q = lane >> 4, r15 = lane & 15;
        int col = t2 * 16 + r15;
        #pragma unroll
        for (int j = 0; j < 8; ++j) {
            int k = s * 32 + q * 8 + j;
            float v = (col < LH) ? wproj[k * LH + col] : 0.f;
            wfp[(size_t)idx * 8 + j] = (__bf16)v;
        }
    }
}

// ---------------------------------------------------------------------------
// K0c: swizzle GEMM weights into MFMA B-fragment order, bf16.
__global__ __launch_bounds__(256) void wswizzle_kernel(
    const float* __restrict__ gat_w, const float* __restrict__ gate_w1,
    __bf16* __restrict__ wf) {
    int b = blockIdx.x;           // l*32 + y*8 + ks
    int l = b >> 5;
    int rem = b & 31;
    int y = rem >> 3, ks = rem & 7;
    int tid = threadIdx.x;
    int t = tid >> 6, lane = tid & 63;
    int q = lane >> 4, r15 = lane & 15;
    const float* W = (l < 5) ? (gat_w + (size_t)l * DD * DD) : gate_w1;
    size_t obase = (((size_t)b * 4 + t) * 64 + lane) * 8;
    int kbase = ks * 32 + q * 8;
    int col = y * 64 + t * 16 + r15;
    #pragma unroll
    for (int j = 0; j < 8; ++j)
        wf[obase + j] = (__bf16)W[(size_t)(kbase + j) * DD + col];
}

// ---------------------------------------------------------------------------
// K1: node encoder h = relu(x @ enc_w + enc_b); also writes bf16 shadow
__global__ __launch_bounds__(256) void encoder_kernel(
    const float* __restrict__ x, const float* __restrict__ enc_w,
    const float* __restrict__ enc_b, float* __restrict__ h,
    __bf16* __restrict__ hbf, int N) {
    int n = blockIdx.x;
    int tid = threadIdx.x;
    __shared__ float xs[42];
    if (tid < 42) xs[tid] = x[(size_t)n * 42 + tid];
    __syncthreads();
    float acc = enc_b[tid];
    #pragma unroll
    for (int f = 0; f < 42; ++f) acc += xs[f] * enc_w[f * DD + tid];
    float v = fmaxf(acc, 0.f);
    h[(size_t)n * DD + tid] = v;
    hbf[(size_t)n * DD + tid] = (__bf16)v;
}

// ---------------------------------------------------------------------------
// K2 v6: edge_pre on matrix cores; output written in CSR order via pos[e]
// (so downstream reads of a_e are contiguous in k, csr_eid eliminated).
__global__ __launch_bounds__(256) void edge_mfma_kernel(
    const float* __restrict__ edge_attr, const __bf16* __restrict__ wfe,
    const __bf16* __restrict__ wfp, const int* __restrict__ pos,
    float* __restrict__ a_e_csr, int E) {
    __shared__ __bf16 sm[4][16][264];   // 33 KB
    int tid = threadIdx.x;
    int w = tid >> 6, lane = tid & 63;
    int q = lane >> 4, r15 = lane & 15;
    int eb = blockIdx.x * 64 + w * 16;
    int e = eb + r15;
    int ec = min(e, E - 1);
    bf16x8 a1;
    #pragma unroll
    for (int j = 0; j < 8; ++j) a1[j] = (__bf16)0.f;
    if (q == 0) {
        const float4* p = (const float4*)(edge_attr + (size_t)ec * 12);
        float4 p0 = p[0], p1 = p[1];
        a1[0] = (__bf16)p0.x; a1[1] = (__bf16)p0.y; a1[2] = (__bf16)p0.z; a1[3] = (__bf16)p0.w;
        a1[4] = (__bf16)p1.x; a1[5] = (__bf16)p1.y; a1[6] = (__bf16)p1.z; a1[7] = (__bf16)p1.w;
    } else if (q == 1) {
        float4 p2 = *(const float4*)(edge_attr + (size_t)ec * 12 + 8);
        a1[0] = (__bf16)p2.x; a1[1] = (__bf16)p2.y; a1[2] = (__bf16)p2.z; a1[3] = (__bf16)p2.w;
        a1[4] = (__bf16)1.0f;  // k = 12: bias row
    }
    const bf16x8* wfeP = (const bf16x8*)wfe;
    f32x4 zero = (f32x4){0.f, 0.f, 0.f, 0.f};
    #pragma unroll
    for (int t = 0; t < 16; ++t) {
        bf16x8 bfr = wfeP[t * 64 + lane];
        f32x4 c = __builtin_amdgcn_mfma_f32_16x16x32_bf16(a1, bfr, zero, 0, 0, 0);
        int col = t * 16 + r15;
        #pragma unroll
        for (int r = 0; r < 4; ++r)
            sm[w][q * 4 + r][col] = (__bf16)fmaxf(c[r], 0.f);
    }
    const bf16x8* wfpP = (const bf16x8*)wfp;
    f32x4 c2[2];
    c2[0] = zero; c2[1] = zero;
    #pragma unroll
    for (int s = 0; s < 8; ++s) {
        bf16x8 a2 = *(const bf16x8*)&sm[w][r15][s * 32 + q * 8];
        #pragma unroll
        for (int t2 = 0; t2 < 2; ++t2)
            c2[t2] = __builtin_amdgcn_mfma_f32_16x16x32_bf16(
                a2, wfpP[(s * 2 + t2) * 64 + lane], c2[t2], 0, 0, 0);
    }
    #pragma unroll
    for (int t2 = 0; t2 < 2; ++t2) {
        int col = t2 * 16 + r15;
        if (col >= LH) continue;
        #pragma unroll
        for (int r = 0; r < 4; ++r) {
            int e2 = eb + q * 4 + r;
            if (e2 < E) {
                int pk = pos[e2];
                a_e_csr[(size_t)pk * LH + col] = c2[t2][r];
            }
        }
    }
}

// ---------------------------------------------------------------------------
__global__ void deg_kernel(const int* __restrict__ dst, int* __restrict__ deg, int E) {
    int e = blockIdx.x * 256 + threadIdx.x;
    if (e < E) atomicAdd(&deg[dst[e]], 1);
}

// K3: self-loop a_e = mean of incoming (contiguous CSR rows now)
__global__ void self_ae_kernel(const int* __restrict__ row_ptr,
                               float* __restrict__ a_e_csr, int N, int E) {
    int i = blockIdx.x * 256 + threadIdx.x;
    if (i >= N * LH) return;
    int n = i / LH;
    int j = i % LH;
    int rs = row_ptr[n], re = row_ptr[n + 1];
    float s = 0.f;
    for (int k = rs; k < re; ++k)
        s += a_e_csr[(size_t)k * LH + j];
    a_e_csr[(size_t)(E + n) * LH + j] = s / (float)max(re - rs, 1);
}

// K4 v2: exclusive scan deg -> row_ptr+cursor; shuffle-based (4 barriers/chunk)
__global__ __launch_bounds__(1024) void scan_kernel(const int* __restrict__ deg,
                                                    int* __restrict__ row_ptr,
                                                    int* __restrict__ cursor, int n) {
    __shared__ int wsum[16];
    __shared__ int carry_s;
    int tid = threadIdx.x;
    int w = tid >> 6, lane = tid & 63;
    if (tid == 0) carry_s = 0;
    __syncthreads();
    for (int base = 0; base < n; base += 1024) {
        int i = base + tid;
        int v = (i < n) ? deg[i] : 0;
        int carry = carry_s;
        // inclusive wave scan
        int s = v;
        #pragma unroll
        for (int off = 1; off < 64; off <<= 1) {
            int t = __shfl_up(s, off, 64);
            if (lane >= off) s += t;
        }
        if (lane == 63) wsum[w] = s;
        __syncthreads();
        if (w == 0 && lane < 16) {
            int ws = wsum[lane];
            #pragma unroll
            for (int off = 1; off < 16; off <<= 1) {
                int t = __shfl_up(ws, off, 64);
                if (lane >= off) ws += t;
            }
            wsum[lane] = ws;  // inclusive wave prefix
        }
        __syncthreads();
        int waveoff = (w == 0) ? 0 : wsum[w - 1];
        if (i < n) {
            int ex = carry + waveoff + s - v;
            row_ptr[i] = ex;
            cursor[i] = ex;
        }
        __syncthreads();
        if (tid == 0) carry_s = carry + wsum[15];
        __syncthreads();
    }
    if (tid == 0) row_ptr[n] = carry_s;
}

// K4c: scatter edges into CSR order by dst; also emit inverse perm pos[e]
__global__ void scatter_kernel(const int* __restrict__ src, const int* __restrict__ dst,
                               int* __restrict__ cursor, int* __restrict__ csr_src,
                               int* __restrict__ pos, int E) {
    int e = blockIdx.x * 256 + threadIdx.x;
    if (e >= E) return;
    int d = dst[e];
    int pk = atomicAdd(&cursor[d], 1);
    csr_src[pk] = src[e];
    pos[e] = pk;
}

// ---------------------------------------------------------------------------
// MFMA GEMM: xhbf[M,256] (bf16) = hbf @ W. 64x64 tile/block, blockIdx.y = head.
// No LDS/barriers. Fused epilogues (a_s/a_d or gate).
__global__ __launch_bounds__(256) void gemm_mfma_kernel(
    const __bf16* __restrict__ hbf, const __bf16* __restrict__ wf,
    __bf16* __restrict__ xhbf, int M,
    const float* __restrict__ att_src, const float* __restrict__ att_dst,
    float* __restrict__ a_s, float* __restrict__ a_d,
    const float* __restrict__ bias, const float* __restrict__ gate_w2,
    const float* __restrict__ gate_b2, float* __restrict__ gate_out) {
    int tid = threadIdx.x;
    int w = tid >> 6, lane = tid & 63;
    int q = lane >> 4, r15 = lane & 15;
    int m0 = blockIdx.x * 64;
    int y = blockIdx.y;
    int arow = m0 + w * 16 + r15;
    int arowc = min(arow, M - 1);
    const __bf16* ap = hbf + (size_t)arowc * DD + q * 8;
    const bf16x8* bp0 = (const bf16x8*)wf + (size_t)(y * 8) * 4 * 64 + lane;
    f32x4 acc[4];
    #pragma unroll
    for (int t = 0; t < 4; ++t) acc[t] = (f32x4){0.f, 0.f, 0.f, 0.f};
    #pragma unroll
    for (int ks = 0; ks < 8; ++ks) {
        bf16x8 a = *(const bf16x8*)(ap + ks * 32);
        const bf16x8* bp = bp0 + (size_t)ks * 4 * 64;
        #pragma unroll
        for (int t = 0; t < 4; ++t) {
            bf16x8 b = bp[(size_t)t * 64];
            acc[t] = __builtin_amdgcn_mfma_f32_16x16x32_bf16(a, b, acc[t], 0, 0, 0);
        }
    }
    if (xhbf) {
        #pragma unroll
        for (int t = 0; t < 4; ++t) {
            int col = y * 64 + t * 16 + r15;
            #pragma unroll
            for (int r = 0; r < 4; ++r) {
                int rc = m0 + w * 16 + q * 4 + r;
                if (rc < M) xhbf[(size_t)rc * DD + col] = (__bf16)acc[t][r];
            }
        }
    }
    if (att_src) {
        #pragma unroll
        for (int r = 0; r < 4; ++r) {
            float ps = 0.f, pd = 0.f;
            #pragma unroll
            for (int t = 0; t < 4; ++t) {
                int col = y * 64 + t * 16 + r15;
                ps += acc[t][r] * att_src[col];
                pd += acc[t][r] * att_dst[col];
            }
            #pragma unroll
            for (int mask = 1; mask < 16; mask <<= 1) {
                ps += __shfl_xor(ps, mask, 64);
                pd += __shfl_xor(pd, mask, 64);
            }
            int rc = m0 + w * 16 + q * 4 + r;
            if (r15 == 0 && rc < M) {
                a_s[rc * HH + y] = ps;
                a_d[rc * HH + y] = pd;
            }
        }
    }
    if (gate_w2) {
        #pragma unroll
        for (int r = 0; r < 4; ++r) {
            float pg = 0.f;
            #pragma unroll
            for (int t = 0; t < 4; ++t) {
                int col = y * 64 + t * 16 + r15;
                pg += fmaxf(acc[t][r] + bias[col], 0.f) * gate_w2[col];
            }
            #pragma unroll
            for (int mask = 1; mask < 16; mask <<= 1) pg += __shfl_xor(pg, mask, 64);
            int rc = m0 + w * 16 + q * 4 + r;
            if (r15 == 0 && rc < M) {
                float add = pg + (y == 0 ? gate_b2[0] : 0.f);
                atomicAdd(&gate_out[rc], add);
            }
        }
    }
}

// ---------------------------------------------------------------------------
// K6 v6: WAVE-PER-NODE; a_e read contiguously (CSR order); pass-3 gather
// unrolled x2 for memory-level parallelism.
__global__ __launch_bounds__(256) void gat_message6_kernel(
    const __bf16* __restrict__ xhbf, const float* __restrict__ a_s,
    const float* __restrict__ a_d, const float* __restrict__ a_e,  // +l*4; [k][20]
    const int* __restrict__ row_ptr, const int* __restrict__ csr_src,
    const float* __restrict__ gat_b,
    const float* __restrict__ ln_g, const float* __restrict__ ln_b,
    float* __restrict__ h, __bf16* __restrict__ hbf, int N, int E) {
    __shared__ float lws[4][WCAP * 4];   // 12 KB: [wave][kk*4 + head]
    int tid = threadIdx.x;
    int w = tid >> 6, lane = tid & 63;
    int n = blockIdx.x * 4 + w;
    if (n >= N) return;
    int hh = lane >> 4, j = lane & 15;
    int rs = row_ptr[n], re = row_ptr[n + 1];
    int deg = re - rs;
    float adn = a_d[n * HH + hh];
    float al_self = lrelu(a_s[n * HH + hh] + adn + a_e[(size_t)(E + n) * LH + hh]);
    float m = al_self, den = 0.f;
    for (int k = rs + j; k < re; k += 16) {
        int kk = k - rs;
        int s = csr_src[k];
        float a = lrelu(a_s[s * HH + hh] + adn + a_e[(size_t)k * LH + hh]);
        if (kk < WCAP) lws[w][kk * 4 + hh] = a;
        float mn = fmaxf(m, a);
        den = den * __expf(m - mn) + __expf(a - mn);
        m = mn;
    }
    #pragma unroll
    for (int off = 1; off < 16; off <<= 1) {
        float m2 = __shfl_xor(m, off, 64);
        float d2 = __shfl_xor(den, off, 64);
        float mn = fmaxf(m, m2);
        den = den * __expf(m - mn) + d2 * __expf(m2 - mn);
        m = mn;
    }
    den += __expf(al_self - m);
    float inv_den = 1.0f / den;
    int cap = min(deg, WCAP);
    for (int kk = j; kk < cap; kk += 16)
        lws[w][kk * 4 + hh] = __expf(lws[w][kk * 4 + hh] - m) * inv_den;
    float wself = __expf(al_self - m) * inv_den;
    bf16x4 xsb = *((const bf16x4*)(xhbf + (size_t)n * DD) + lane);
    float4 acc;
    acc.x = wself * (float)xsb[0]; acc.y = wself * (float)xsb[1];
    acc.z = wself * (float)xsb[2]; acc.w = wself * (float)xsb[3];
    int k = rs;
    for (; k + 1 < re; k += 2) {
        int kk0 = k - rs, kk1 = kk0 + 1;
        int s0 = csr_src[k], s1_ = csr_src[k + 1];
        float w0, w1;
        if (kk0 < WCAP) w0 = lws[w][kk0 * 4 + hh];
        else w0 = __expf(lrelu(a_s[s0 * HH + hh] + adn + a_e[(size_t)k * LH + hh]) - m) * inv_den;
        if (kk1 < WCAP) w1 = lws[w][kk1 * 4 + hh];
        else w1 = __expf(lrelu(a_s[s1_ * HH + hh] + adn + a_e[(size_t)(k + 1) * LH + hh]) - m) * inv_den;
        bf16x4 x0 = *((const bf16x4*)(xhbf + (size_t)s0 * DD) + lane);
        bf16x4 x1 = *((const bf16x4*)(xhbf + (size_t)s1_ * DD) + lane);
        acc.x += w0 * (float)x0[0] + w1 * (float)x1[0];
        acc.y += w0 * (float)x0[1] + w1 * (float)x1[1];
        acc.z += w0 * (float)x0[2] + w1 * (float)x1[2];
        acc.w += w0 * (float)x0[3] + w1 * (float)x1[3];
    }
    if (k < re) {
        int kk0 = k - rs;
        int s0 = csr_src[k];
        float w0;
        if (kk0 < WCAP) w0 = lws[w][kk0 * 4 + hh];
        else w0 = __expf(lrelu(a_s[s0 * HH + hh] + adn + a_e[(size_t)k * LH + hh]) - m) * inv_den;
        bf16x4 x0 = *((const bf16x4*)(xhbf + (size_t)s0 * DD) + lane);
        acc.x += w0 * (float)x0[0]; acc.y += w0 * (float)x0[1];
        acc.z += w0 * (float)x0[2]; acc.w += w0 * (float)x0[3];
    }
    float4 gb = *((const float4*)gat_b + lane);
    float4 val;
    val.x = acc.x + gb.x; val.y = acc.y + gb.y;
    val.z = acc.z + gb.z; val.w = acc.w + gb.w;
    float s1 = val.x + val.y + val.z + val.w;
    float s2 = val.x * val.x + val.y * val.y + val.z * val.z + val.w * val.w;
    #pragma unroll
    for (int off = 1; off < 64; off <<= 1) {
        s1 += __shfl_xor(s1, off, 64);
        s2 += __shfl_xor(s2, off, 64);
    }
    float mu = s1 * (1.0f / DD);
    float var = s2 * (1.0f / DD) - mu * mu;
    float rstd = rsqrtf(var + 1e-5f);
    float4 lg = *((const float4*)ln_g + lane);
    float4 lb = *((const float4*)ln_b + lane);
    float4 nv;
    nv.x = fmaxf((val.x - mu) * rstd * lg.x + lb.x, 0.f);
    nv.y = fmaxf((val.y - mu) * rstd * lg.y + lb.y, 0.f);
    nv.z = fmaxf((val.z - mu) * rstd * lg.z + lb.z, 0.f);
    nv.w = fmaxf((val.w - mu) * rstd * lg.w + lb.w, 0.f);
    float4* hp = (float4*)(h + (size_t)n * DD) + lane;
    float4 hv = *hp;
    hv.x += nv.x; hv.y += nv.y; hv.z += nv.z; hv.w += nv.w;
    *hp = hv;
    bf16x4 hb;
    hb[0] = (__bf16)hv.x; hb[1] = (__bf16)hv.y;
    hb[2] = (__bf16)hv.z; hb[3] = (__bf16)hv.w;
    *((bf16x4*)(hbf + (size_t)n * DD) + lane) = hb;
}

// ---------------------------------------------------------------------------
__global__ void bstart_kernel(const int* __restrict__ batch, int* __restrict__ bstart,
                              int N, int B) {
    int b = threadIdx.x;
    if (b > B) return;
    int lo = 0, hi = N;
    while (lo < hi) {
        int mid = (lo + hi) >> 1;
        if (batch[mid] < b) lo = mid + 1; else hi = mid;
    }
    bstart[b] = lo;
}

__global__ __launch_bounds__(256) void gseg_kernel(
    const float* __restrict__ gate, const int* __restrict__ bstart,
    float* __restrict__ gmax, float* __restrict__ gden) {
    int b = blockIdx.x;
    int tid = threadIdx.x;
    int s0 = bstart[b], s1 = bstart[b + 1];
    __shared__ float red[256];
    float m = -1e30f;
    for (int i = s0 + tid; i < s1; i += 256) m = fmaxf(m, gate[i]);
    red[tid] = m;
    __syncthreads();
    for (int off = 128; off; off >>= 1) {
        if (tid < off) red[tid] = fmaxf(red[tid], red[tid + off]);
        __syncthreads();
    }
    float gm = red[0];
    __syncthreads();
    float s = 0.f;
    for (int i = s0 + tid; i < s1; i += 256) s += __expf(gate[i] - gm);
    red[tid] = s;
    __syncthreads();
    for (int off = 128; off; off >>= 1) {
        if (tid < off) red[tid] += red[tid + off];
        __syncthreads();
    }
    if (tid == 0) {
        gmax[b] = gm;
        gden[b] = red[0];
    }
}

// K7d: pooled embedding; softmax weight computed inline.
#define POOL_CHUNK 32
__global__ __launch_bounds__(256) void pool_scatter_kernel(
    const float* __restrict__ h, const float* __restrict__ gate,
    const float* __restrict__ gmax, const float* __restrict__ gden,
    const int* __restrict__ batch, float* __restrict__ g_embed, int N) {
    int i0 = blockIdx.x * POOL_CHUNK;
    int d = threadIdx.x;
    int iend = min(i0 + POOL_CHUNK, N);
    float acc = 0.f;
    int cur = batch[i0];
    for (int i = i0; i < iend; ++i) {
        int b = batch[i];
        if (b != cur) {
            atomicAdd(&g_embed[cur * DD + d], acc);
            acc = 0.f;
            cur = b;
        }
        float wgt = __expf(gate[i] - gmax[b]) / gden[b];
        acc += wgt * h[(size_t)i * DD + d];
    }
    atomicAdd(&g_embed[cur * DD + d], acc);
}

__global__ __launch_bounds__(256) void readout_kernel(
    const float* __restrict__ g_embed, const float* __restrict__ w1,
    const float* __restrict__ b1, const float* __restrict__ w2,
    const float* __restrict__ b2, float* __restrict__ out) {
    int b = blockIdx.x;
    int tid = threadIdx.x;
    __shared__ float gvec[256];
    __shared__ float hid[256];
    gvec[tid] = g_embed[b * DD + tid];
    __syncthreads();
    float hv = b1[tid];
    for (int k = 0; k < DD; ++k) hv += gvec[k] * w1[k * DD + tid];
    hid[tid] = fmaxf(hv, 0.f);
    __syncthreads();
    float o = b2[tid];
    for (int t = 0; t < DD; ++t) o += hid[t] * w2[t * DD + tid];
    out[b * DD + tid] = o;
}

// ---------------------------------------------------------------------------
extern "C" void kernel_launch(void* const* d_in, const int* in_sizes, int n_in,
                              void* d_out, int out_size, void* d_ws, size_t ws_size,
                              hipStream_t stream) {
    const float* x        = (const float*)d_in[0];
    const float* edge_attr= (const float*)d_in[1];
    const int*   edge_idx = (const int*)d_in[2];
    const int*   batch    = (const int*)d_in[3];
    const float* enc_w    = (const float*)d_in[4];
    const float* enc_b    = (const float*)d_in[5];
    const float* eenc_w   = (const float*)d_in[6];
    const float* eenc_b   = (const float*)d_in[7];
    const float* gat_w    = (const float*)d_in[8];
    const float* att_src  = (const float*)d_in[9];
    const float* att_dst  = (const float*)d_in[10];
    const float* att_edge = (const float*)d_in[11];
    const float* gat_ew   = (const float*)d_in[12];
    const float* gat_b    = (const float*)d_in[13];
    const float* ln_g     = (const float*)d_in[14];
    const float* ln_b     = (const float*)d_in[15];
    const float* gate_w1  = (const float*)d_in[16];
    const float* gate_b1  = (const float*)d_in[17];
    const float* gate_w2  = (const float*)d_in[18];
    const float* gate_b2  = (const float*)d_in[19];
    const float* ro_w1    = (const float*)d_in[20];
    const float* ro_b1    = (const float*)d_in[21];
    const float* ro_w2    = (const float*)d_in[22];
    const float* ro_b2    = (const float*)d_in[23];
    float* out = (float*)d_out;

    const int N = in_sizes[0] / 42;       // 10000
    const int E = in_sizes[1] / 12;       // 160000
    const int B = out_size / DD;          // 16

    // workspace carve-up
    char* p = (char*)d_ws;
    auto alloc = [&](size_t bytes) {
        char* r = p;
        p += (bytes + 255) & ~(size_t)255;
        return (void*)r;
    };
    float*  h       = (float*)alloc((size_t)N * DD * 4);
    __bf16* hbf     = (__bf16*)alloc((size_t)N * DD * 2);
    __bf16* xhbf    = (__bf16*)alloc((size_t)N * DD * 2);
    float*  a_s     = (float*)alloc((size_t)N * HH * 4);
    float*  a_d     = (float*)alloc((size_t)N * HH * 4);
    float*  a_e_csr = (float*)alloc((size_t)(E + N) * LH * 4);  // CSR order + self rows
    float*  wproj   = (float*)alloc((size_t)DD * LH * 4);
    __bf16* wfe     = (__bf16*)alloc((size_t)16 * 64 * 8 * 2);
    __bf16* wfp     = (__bf16*)alloc((size_t)16 * 64 * 8 * 2);
    __bf16* wf      = (__bf16*)alloc((size_t)6 * DD * DD * 2);
    float*  gate    = (float*)alloc((size_t)N * 4);
    float*  g_embed = (float*)alloc((size_t)B * DD * 4);
    float*  gmax    = (float*)alloc((size_t)B * 4);
    float*  gden    = (float*)alloc((size_t)B * 4);
    int* deg        = (int*)alloc((size_t)N * 4);
    int* row_ptr    = (int*)alloc((size_t)(N + 1) * 4);
    int* cursor     = (int*)alloc((size_t)N * 4);
    int* csr_src    = (int*)alloc((size_t)E * 4);
    int* pos        = (int*)alloc((size_t)E * 4);
    int* bstart     = (int*)alloc((size_t)(B + 1) * 4);

    const int* src_arr = edge_idx;
    const int* dst_arr = edge_idx + E;

    hipMemsetAsync(deg, 0, (size_t)N * 4, stream);
    hipMemsetAsync(g_embed, 0, (size_t)B * DD * 4, stream);
    hipMemsetAsync(gate, 0, (size_t)N * 4, stream);

    wproj_kernel<<<LL, 256, 0, stream>>>(gat_ew, att_edge, wproj);
    pack_edge_frags_kernel<<<1, 256, 0, stream>>>(eenc_w, eenc_b, wproj, wfe, wfp);
    wswizzle_kernel<<<192, 256, 0, stream>>>(gat_w, gate_w1, wf);
    encoder_kernel<<<N, 256, 0, stream>>>(x, enc_w, enc_b, h, hbf, N);
    deg_kernel<<<(E + 255) / 256, 256, 0, stream>>>(dst_arr, deg, E);
    scan_kernel<<<1, 1024, 0, stream>>>(deg, row_ptr, cursor, N);
    scatter_kernel<<<(E + 255) / 256, 256, 0, stream>>>(
        src_arr, dst_arr, cursor, csr_src, pos, E);
    edge_mfma_kernel<<<(E + 63) / 64, 256, 0, stream>>>(
        edge_attr, wfe, wfp, pos, a_e_csr, E);
    self_ae_kernel<<<(N * LH + 255) / 256, 256, 0, stream>>>(
        row_ptr, a_e_csr, N, E);

    dim3 ggrid((N + 63) / 64, 4);
    for (int l = 0; l < LL; ++l) {
        gemm_mfma_kernel<<<ggrid, 256, 0, stream>>>(
            hbf, wf + (size_t)l * DD * DD, xhbf, N,
            att_src + l * DD, att_dst + l * DD, a_s, a_d,
            nullptr, nullptr, nullptr, nullptr);
        gat_message6_kernel<<<(N + 3) / 4, 256, 0, stream>>>(
            xhbf, a_s, a_d, a_e_csr + l * HH, row_ptr, csr_src,
            gat_b + l * DD, ln_g + l * DD, ln_b + l * DD, h, hbf, N, E);
    }

    // pooling gate: gate[n] = relu(h@gate_w1+b1) . gate_w2 + b2, fused MFMA
    gemm_mfma_kernel<<<ggrid, 256, 0, stream>>>(
        hbf, wf + (size_t)5 * DD * DD, nullptr, N,
        nullptr, nullptr, nullptr, nullptr,
        gate_b1, gate_w2, gate_b2, gate);
    bstart_kernel<<<1, 32, 0, stream>>>(batch, bstart, N, B);
    gseg_kernel<<<B, 256, 0, stream>>>(gate, bstart, gmax, gden);
    pool_scatter_kernel<<<(N + POOL_CHUNK - 1) / POOL_CHUNK, 256, 0, stream>>>(
        h, gate, gmax, gden, batch, g_embed, N);
    readout_kernel<<<B, 256, 0, stream>>>(g_embed, ro_w1, ro_b1, ro_w2, ro_b2, out);
}